// Round 13
// baseline (521.815 us; speedup 1.0000x reference)
//
#include <hip/hip_runtime.h>
#include <hip/hip_fp16.h>

#define NM 131072   // mol nodes
#define EM 524288   // mol edges
#define NG 4096     // graphs
#define DM 6        // mol in dim
#define NP 100000   // prot nodes
#define EP 1600000  // prot edges
#define DP 20       // prot in dim

static inline int cdiv(int a, int b){ return (a + b - 1) / b; }

__device__ __forceinline__ float leaky(float x){ return x > 0.f ? x : 0.2f * x; }

union H8 { float4 f4; __half2 h2[4]; };

// ================= bucketed CSR build (round-7, proven) =================
template<int CHUNK>
__global__ void k_coarse_hist(const int* __restrict__ dst, int* __restrict__ coarse,
                              int E, int K){
    __shared__ int lh[512];
    int t = threadIdx.x;
    for (int i = t; i < K; i += 256) lh[i] = 0;
    __syncthreads();
    int base = blockIdx.x * CHUNK;
    int end = min(base + CHUNK, E);
    for (int e = base + t; e < end; e += 256)
        atomicAdd(&lh[dst[e] >> 8], 1);
    __syncthreads();
    for (int i = t; i < K; i += 256)
        if (lh[i]) atomicAdd(&coarse[i], lh[i]);
}

__global__ void k_coarse_scan(const int* __restrict__ coarse, int* __restrict__ cstart,
                              int* __restrict__ cursor, int K, int E){
    int t = threadIdx.x, lane = t & 63, wid = t >> 6;
    int v0 = (t < K) ? coarse[t] : 0;
    int v = v0;
    #pragma unroll
    for (int off = 1; off < 64; off <<= 1) {
        int x = __shfl_up(v, off, 64);
        if (lane >= off) v += x;
    }
    __shared__ int ws[8];
    if (lane == 63) ws[wid] = v;
    __syncthreads();
    int add = 0;
    for (int w = 0; w < wid; w++) add += ws[w];
    int excl = v + add - v0;
    if (t < K) { cstart[t] = excl; cursor[t] = excl; }
    if (t == K - 1) cstart[K] = excl + v0;
}

template<int CHUNK, int EPT>
__global__ void k_part(const int* __restrict__ ei, int* __restrict__ cursor,
                       unsigned* __restrict__ buf, int E, int K){
    __shared__ int lh[512];
    __shared__ int lbase[512];
    int t = threadIdx.x;
    for (int i = t; i < K; i += 256) lh[i] = 0;
    __syncthreads();
    int base = blockIdx.x * CHUNK;
    int end = min(base + CHUNK, E);
    unsigned pay[EPT]; int bslot[EPT];
    int cnt = 0;
    for (int e = base + t; e < end; e += 256) {
        int u = ei[e], v = ei[E + e];
        int b = v >> 8;
        int ls = atomicAdd(&lh[b], 1);
        pay[cnt] = ((unsigned)(v & 255) << 24) | (unsigned)u;
        bslot[cnt] = (b << 13) | ls;
        cnt++;
    }
    __syncthreads();
    for (int i = t; i < K; i += 256)
        lbase[i] = lh[i] ? atomicAdd(&cursor[i], lh[i]) : 0;
    __syncthreads();
    for (int j = 0; j < cnt; j++) {
        int b = bslot[j] >> 13, ls = bslot[j] & 8191;
        buf[lbase[b] + ls] = pay[j];
    }
}

// fine: writes PACKED rp (start | deg<<OBITS) and optionally dinv directly
template<int OBITS, int DINV>
__global__ void k_fine(const unsigned* __restrict__ buf, const int* __restrict__ cstart,
                       int* __restrict__ rp, int* __restrict__ col,
                       float* __restrict__ dinv, int n, int K){
    int k = blockIdx.x, t = threadIdx.x;
    int start = cstart[k], end = cstart[k + 1];
    __shared__ int cnt[256];
    __shared__ int cur[256];
    cnt[t] = 0;
    __syncthreads();
    for (int p = start + t; p < end; p += 256)
        atomicAdd(&cnt[buf[p] >> 24], 1);
    __syncthreads();
    int v0 = cnt[t];
    int lane = t & 63, wid = t >> 6;
    int v = v0;
    #pragma unroll
    for (int off = 1; off < 64; off <<= 1) {
        int x = __shfl_up(v, off, 64);
        if (lane >= off) v += x;
    }
    __shared__ int ws[4];
    if (lane == 63) ws[wid] = v;
    __syncthreads();
    int add = 0;
    for (int w = 0; w < wid; w++) add += ws[w];
    int excl = v + add - v0;
    int ofs = start + excl;
    cur[t] = ofs;
    int idx = (k << 8) + t;
    if (idx < n) {
        rp[idx] = (int)((unsigned)ofs | ((unsigned)v0 << OBITS));
        if (DINV) dinv[idx] = rsqrtf((float)(v0 + 1));
    }
    __syncthreads();
    for (int p = start + t; p < end; p += 256) {
        unsigned pk = buf[p];
        int slot = atomicAdd(&cur[pk >> 24], 1);
        col[slot] = (int)(pk & 0xFFFFFFu);
    }
}

// ---------------- fused: mol x -> padded 8-half rows  +  segment bounds ----------------
__global__ void k_molprep(const float* __restrict__ x, __half* __restrict__ x8,
                          const int* __restrict__ batch, int* __restrict__ gstart,
                          int* __restrict__ gend, int n, int nbA){
    int b = blockIdx.x;
    if (b < nbA) {
        int i = b * 256 + threadIdx.x;
        if (i >= n) return;
        H8 r;
        #pragma unroll
        for (int k = 0; k < 3; k++)
            r.h2[k] = __floats2half2_rn(x[i*6 + 2*k], x[i*6 + 2*k + 1]);
        r.h2[3] = __floats2half2_rn(0.f, 0.f);
        *(float4*)&x8[(size_t)i * 8] = r.f4;
    } else {
        int i = (b - nbA) * 256 + threadIdx.x;
        if (i >= n) return;
        int g = batch[i];
        if (i == 0 || batch[i - 1] != g) gstart[g] = i;
        if (i == n - 1 || batch[i + 1] != g) gend[g] = i + 1;
    }
}

// ---------------- prep: prot x -> padded 32-half rows + es/ed dots ----------------
__global__ void k_prep_prot(const float* __restrict__ x, const float* __restrict__ W1,
                            const float* __restrict__ as_, const float* __restrict__ ad_,
                            __half* __restrict__ x32, float* __restrict__ es,
                            float* __restrict__ ed_, int n){
    __shared__ float vas[20], vds[20];
    int t = threadIdx.x;
    if (t < 20) {
        float s = 0.f;
        for (int j = 0; j < 64; j++) s += W1[t * 64 + j] * as_[j];
        vas[t] = s;
    } else if (t >= 32 && t < 52) {
        int k = t - 32;
        float s = 0.f;
        for (int j = 0; j < 64; j++) s += W1[k * 64 + j] * ad_[j];
        vds[k] = s;
    }
    __syncthreads();
    int i = blockIdx.x * 256 + t;
    if (i >= n) return;
    float xv[20];
    float s = 0.f, d = 0.f;
    #pragma unroll
    for (int k = 0; k < 20; k++) {
        xv[k] = x[i*20 + k];
        s += xv[k] * vas[k]; d += xv[k] * vds[k];
    }
    es[i] = s; ed_[i] = d;
    H8 r0, r1, r2, rz;
    #pragma unroll
    for (int k = 0; k < 4; k++) r0.h2[k] = __floats2half2_rn(xv[2*k],   xv[2*k+1]);
    #pragma unroll
    for (int k = 0; k < 4; k++) r1.h2[k] = __floats2half2_rn(xv[8+2*k], xv[9+2*k]);
    r2.h2[0] = __floats2half2_rn(xv[16], xv[17]);
    r2.h2[1] = __floats2half2_rn(xv[18], xv[19]);
    r2.h2[2] = __floats2half2_rn(0.f, 0.f);
    r2.h2[3] = __floats2half2_rn(0.f, 0.f);
    rz.h2[0] = rz.h2[1] = rz.h2[2] = rz.h2[3] = __floats2half2_rn(0.f, 0.f);
    *(float4*)&x32[(size_t)i * 32]      = r0.f4;
    *(float4*)&x32[(size_t)i * 32 + 8]  = r1.f4;
    *(float4*)&x32[(size_t)i * 32 + 16] = r2.f4;
    *(float4*)&x32[(size_t)i * 32 + 24] = rz.f4;
}

// ---------------- mol L1 gather: 8 lanes/node, 8 nodes/wave, inline dinv ----------------
__global__ void k_gather_x8(const int* __restrict__ rp, const int* __restrict__ col,
                            const __half* __restrict__ x8, const float* __restrict__ dinv,
                            float* __restrict__ agg){
    __shared__ float ost[192];
    int tid = threadIdx.x;
    int wv = tid >> 6, l = tid & 63, g = l >> 3, q = l & 7;
    int node = (blockIdx.x << 5) + (wv << 3) + g;
    unsigned pk = (unsigned)rp[node];
    int s0 = (int)(pk & 0xFFFFFu);
    int deg = (int)(pk >> 20);
    float dd = dinv[node];
    float acc[6] = {0.f,0.f,0.f,0.f,0.f,0.f};
    if (q == 0) {
        H8 r; r.f4 = *(const float4*)&x8[(size_t)node * 8];
        #pragma unroll
        for (int i = 0; i < 3; i++) {
            float2 f = __half22float2(r.h2[i]);
            acc[2*i] = dd * f.x; acc[2*i+1] = dd * f.y;
        }
    }
    for (int base = 0; base < deg; base += 8) {
        int s = base + q;
        int c = col[s0 + s];
        int u = (s < deg) ? c : node;
        float wvv = (s < deg) ? dinv[u] : 0.f;
        H8 r; r.f4 = *(const float4*)&x8[(size_t)u * 8];
        #pragma unroll
        for (int i = 0; i < 3; i++) {
            float2 f = __half22float2(r.h2[i]);
            acc[2*i] += wvv * f.x; acc[2*i+1] += wvv * f.y;
        }
    }
    #pragma unroll
    for (int m = 1; m < 8; m <<= 1) {
        #pragma unroll
        for (int i = 0; i < 6; i++) acc[i] += __shfl_xor(acc[i], m, 8);
    }
    if (q == 0) {
        int slot = (wv << 3) + g;
        #pragma unroll
        for (int i = 0; i < 6; i++) ost[slot * 6 + i] = dd * acc[i];
    }
    __syncthreads();
    if (tid < 48)
        *(float4*)&agg[(size_t)blockIdx.x * 192 + (tid << 2)] = *(float4*)&ost[tid << 2];
}

// ---------------- prot L1 GAT gather: 16 slots x 4 lanes, inline exp weights ----------------
__global__ void k_gather_x32(const int* __restrict__ rp, const int* __restrict__ col,
                             const __half* __restrict__ x32, const float* __restrict__ es,
                             const float* __restrict__ ed_, float* __restrict__ agg){
    int tid = threadIdx.x;
    int node = (blockIdx.x << 2) + (tid >> 6);
    int l = tid & 63, g = l >> 2, q = l & 3;
    unsigned pk = (unsigned)rp[node];
    int s0 = (int)(pk & 0x1FFFFFu);
    int deg = (int)(pk >> 21);
    float edv = ed_[node];
    float selfw = __expf(leaky(es[node] + edv));
    float acc[8] = {0.f,0.f,0.f,0.f,0.f,0.f,0.f,0.f};
    float den = (l == 0) ? selfw : 0.f;
    if (g == 0 && q < 3) {
        H8 r; r.f4 = *(const float4*)&x32[(size_t)node * 32 + (q << 3)];
        #pragma unroll
        for (int i = 0; i < 4; i++) {
            float2 f = __half22float2(r.h2[i]);
            acc[2*i] = selfw * f.x; acc[2*i+1] = selfw * f.y;
        }
    }
    for (int base = 0; base < deg; base += 16) {
        int s = base + g;
        int c = col[s0 + s];
        int u = (s < deg) ? c : node;
        float wvv = (s < deg) ? __expf(leaky(es[u] + edv)) : 0.f;
        if (q < 3) {
            H8 r; r.f4 = *(const float4*)&x32[(size_t)u * 32 + (q << 3)];
            #pragma unroll
            for (int i = 0; i < 4; i++) {
                float2 f = __half22float2(r.h2[i]);
                acc[2*i] += wvv * f.x; acc[2*i+1] += wvv * f.y;
            }
        }
        if (q == 0) den += wvv;
    }
    #pragma unroll
    for (int m = 4; m <= 32; m <<= 1) {
        #pragma unroll
        for (int i = 0; i < 8; i++) acc[i] += __shfl_xor(acc[i], m, 64);
        den += __shfl_xor(den, m, 64);
    }
    den = __shfl(den, 0, 64);
    float inv = 1.f / den;
    if (g == 0) {
        if (q < 2) {
            float4 v0 = make_float4(acc[0]*inv, acc[1]*inv, acc[2]*inv, acc[3]*inv);
            float4 v1 = make_float4(acc[4]*inv, acc[5]*inv, acc[6]*inv, acc[7]*inv);
            *(float4*)&agg[(size_t)node * 20 + (q << 3)]     = v0;
            *(float4*)&agg[(size_t)node * 20 + (q << 3) + 4] = v1;
        } else if (q == 2) {
            float4 v0 = make_float4(acc[0]*inv, acc[1]*inv, acc[2]*inv, acc[3]*inv);
            *(float4*)&agg[(size_t)node * 20 + 16] = v0;
        }
    }
}

// ---------------- fused MLP: agg @ W1 + b1 -> relu -> @ W2 -> fp16 (+att dots) ----------------
template<int D, int ATT>
__global__ void k_mlp(const float* __restrict__ agg, const float* __restrict__ W1,
                      const float* __restrict__ b1, const float* __restrict__ W2,
                      const float* __restrict__ as_, const float* __restrict__ ad_,
                      __half* __restrict__ hout, float* __restrict__ es,
                      float* __restrict__ ed_){
    __shared__ float W1s[D * 64];
    __shared__ float W2s[64 * 64];
    __shared__ float A[16][D + 1];
    __shared__ float X1[16][68];
    int tid = threadIdx.x;
    for (int k = tid; k < D * 64; k += 256) W1s[k] = W1[k];
    for (int k = tid * 4; k < 4096; k += 1024)
        *(float4*)&W2s[k] = *(const float4*)&W2[k];
    int nd = tid >> 4, q = tid & 15;
    size_t node = (size_t)blockIdx.x * 16 + nd;
    for (int k = q; k < D; k += 16) A[nd][k] = agg[node * D + k];
    __syncthreads();
    float4 h1 = *(const float4*)&b1[q << 2];
    #pragma unroll
    for (int k = 0; k < D; k++) {
        float xk = A[nd][k];
        float4 w4 = *(const float4*)&W1s[(k << 6) + (q << 2)];
        h1.x += xk * w4.x; h1.y += xk * w4.y; h1.z += xk * w4.z; h1.w += xk * w4.w;
    }
    h1.x = fmaxf(h1.x, 0.f); h1.y = fmaxf(h1.y, 0.f);
    h1.z = fmaxf(h1.z, 0.f); h1.w = fmaxf(h1.w, 0.f);
    *(float4*)&X1[nd][q << 2] = h1;
    __syncthreads();
    float4 acc = {0.f, 0.f, 0.f, 0.f};
    #pragma unroll 8
    for (int k = 0; k < 64; k++) {
        float xk = X1[nd][k];
        float4 w4 = *(const float4*)&W2s[(k << 6) + (q << 2)];
        acc.x += xk * w4.x; acc.y += xk * w4.y; acc.z += xk * w4.z; acc.w += xk * w4.w;
    }
    union { __half2 h2[2]; float2 f2; } u;
    u.h2[0] = __floats2half2_rn(acc.x, acc.y);
    u.h2[1] = __floats2half2_rn(acc.z, acc.w);
    *(float2*)&hout[node * 64 + (q << 2)] = u.f2;
    if (ATT) {
        int f = q << 2;
        float xa = acc.x * as_[f] + acc.y * as_[f + 1] + acc.z * as_[f + 2] + acc.w * as_[f + 3];
        float ya = acc.x * ad_[f] + acc.y * ad_[f + 1] + acc.z * ad_[f + 2] + acc.w * ad_[f + 3];
        #pragma unroll
        for (int m = 1; m < 16; m <<= 1) {
            xa += __shfl_xor(xa, m, 16);
            ya += __shfl_xor(ya, m, 16);
        }
        if (q == 0) { es[node] = xa; ed_[node] = ya; }
    }
}

// ---------------- layer-2 gather, widened: 16 slots x 4 lanes x 32 B, inline weights ----------------
template<int GAT, int OBITS>
__global__ void k_gather64h(const int* __restrict__ rp, const int* __restrict__ col,
                            const __half* __restrict__ hh, const float* __restrict__ dinv,
                            const float* __restrict__ es, const float* __restrict__ ed_,
                            const float* __restrict__ b, float* __restrict__ out){
    int tid = threadIdx.x;
    int node = (blockIdx.x << 2) + (tid >> 6);
    int l = tid & 63, g = l >> 2, q = l & 3;
    unsigned pk = (unsigned)rp[node];
    int s0 = (int)(pk & ((1u << OBITS) - 1));
    int deg = (int)(pk >> OBITS);
    float edv = GAT ? ed_[node] : 0.f;
    float selfw = GAT ? __expf(leaky(es[node] + edv)) : dinv[node];
    float acc[16];
    #pragma unroll
    for (int i = 0; i < 16; i++) acc[i] = 0.f;
    float den = (l == 0) ? selfw : 0.f;
    if (g == 0) {
        H8 r0, r1;
        r0.f4 = *(const float4*)&hh[(size_t)node * 64 + (q << 4)];
        r1.f4 = *(const float4*)&hh[(size_t)node * 64 + (q << 4) + 8];
        #pragma unroll
        for (int i = 0; i < 4; i++) {
            float2 f0 = __half22float2(r0.h2[i]);
            float2 f1 = __half22float2(r1.h2[i]);
            acc[2*i]     = selfw * f0.x; acc[2*i+1]   = selfw * f0.y;
            acc[8+2*i]   = selfw * f1.x; acc[8+2*i+1] = selfw * f1.y;
        }
    }
    for (int base = 0; base < deg; base += 16) {
        int s = base + g;
        int c = col[s0 + s];
        int u = (s < deg) ? c : node;
        float wvv;
        if (GAT) wvv = (s < deg) ? __expf(leaky(es[u] + edv)) : 0.f;
        else     wvv = (s < deg) ? dinv[u] : 0.f;
        H8 r0, r1;
        r0.f4 = *(const float4*)&hh[(size_t)u * 64 + (q << 4)];
        r1.f4 = *(const float4*)&hh[(size_t)u * 64 + (q << 4) + 8];
        #pragma unroll
        for (int i = 0; i < 4; i++) {
            float2 f0 = __half22float2(r0.h2[i]);
            float2 f1 = __half22float2(r1.h2[i]);
            acc[2*i]     += wvv * f0.x; acc[2*i+1]   += wvv * f0.y;
            acc[8+2*i]   += wvv * f1.x; acc[8+2*i+1] += wvv * f1.y;
        }
        if (GAT && q == 0) den += wvv;
    }
    #pragma unroll
    for (int m = 4; m <= 32; m <<= 1) {
        #pragma unroll
        for (int i = 0; i < 16; i++) acc[i] += __shfl_xor(acc[i], m, 64);
        if (GAT) den += __shfl_xor(den, m, 64);
    }
    if (GAT) den = __shfl(den, 0, 64);
    if (g == 0) {
        float sc = GAT ? (1.f / den) : selfw;
        int f = q << 4;
        #pragma unroll
        for (int c4 = 0; c4 < 4; c4++) {
            float4 v;
            v.x = acc[4*c4]   * sc + b[f + 4*c4];
            v.y = acc[4*c4+1] * sc + b[f + 4*c4 + 1];
            v.z = acc[4*c4+2] * sc + b[f + 4*c4 + 2];
            v.w = acc[4*c4+3] * sc + b[f + 4*c4 + 3];
            *(float4*)&out[(size_t)node * 64 + f + 4*c4] = v;
        }
    }
}

// ---------------- mol pooling ----------------
__global__ void k_segpool(const int* __restrict__ gstart, const int* __restrict__ gend,
                          const float* __restrict__ x, float* __restrict__ gsum){
    int gph = blockIdx.x, t = threadIdx.x;
    int rg = t >> 4, q = t & 15;
    int s = gstart[gph], c = gend[gph] - gstart[gph];
    float4 a = {0.f, 0.f, 0.f, 0.f};
    for (int i = rg; i < c; i += 4) {
        float4 v = *(const float4*)&x[(size_t)(s + i) * 64 + (q << 2)];
        a.x += v.x; a.y += v.y; a.z += v.z; a.w += v.w;
    }
    #pragma unroll
    for (int m = 16; m <= 32; m <<= 1) {
        a.x += __shfl_xor(a.x, m, 64);
        a.y += __shfl_xor(a.y, m, 64);
        a.z += __shfl_xor(a.z, m, 64);
        a.w += __shfl_xor(a.w, m, 64);
    }
    if (rg == 0) *(float4*)&gsum[gph * 64 + (q << 2)] = a;
}

// ---------------- prot pooling ----------------
__global__ void k_pool_prot(const float* __restrict__ x, float* __restrict__ psum, int n){
    __shared__ float red[4][64];
    int t = threadIdx.x, lane = t & 63, wv = t >> 6;
    const float4* x4 = (const float4*)x;
    int total = n * 16;
    float4 a = {0.f, 0.f, 0.f, 0.f};
    for (int i = blockIdx.x * 256 + t; i < total; i += gridDim.x * 256) {
        float4 v = x4[i];
        a.x += v.x; a.y += v.y; a.z += v.z; a.w += v.w;
    }
    #pragma unroll
    for (int m = 16; m <= 32; m <<= 1) {
        a.x += __shfl_xor(a.x, m, 64);
        a.y += __shfl_xor(a.y, m, 64);
        a.z += __shfl_xor(a.z, m, 64);
        a.w += __shfl_xor(a.w, m, 64);
    }
    if (lane < 16) *(float4*)&red[wv][lane << 2] = a;
    __syncthreads();
    if (t < 64) {
        float s = red[0][t] + red[1][t] + red[2][t] + red[3][t];
        atomicAdd(&psum[t], s);
    }
}

// ---------------- fused classifier ----------------
__global__ void k_cls(const float* __restrict__ gsum, const int* __restrict__ gstart,
                      const int* __restrict__ gend, const float* __restrict__ psum,
                      const float* __restrict__ W1, const float* __restrict__ b1,
                      const float* __restrict__ w2, const float* __restrict__ b2,
                      float* __restrict__ out){
    __shared__ float W1s[128 * 64];
    int tid = threadIdx.x;
    for (int k = tid; k < 128 * 64; k += 256) W1s[k] = W1[k];
    __syncthreads();
    int g = blockIdx.x * 4 + (tid >> 6);
    int j = tid & 63;
    float cntf = (float)(gend[g] - gstart[g]);
    float inv = 1.0f / fmaxf(cntf, 1.0f);
    const float invp = 1.0f / (float)NP;
    float acc = b1[j];
    #pragma unroll 8
    for (int k = 0; k < 64; k++) acc += (gsum[g * 64 + k] * inv) * W1s[k * 64 + j];
    #pragma unroll 8
    for (int k = 0; k < 64; k++) acc += (psum[k] * invp) * W1s[(64 + k) * 64 + j];
    float v = fmaxf(acc, 0.f) * w2[j];
    #pragma unroll
    for (int off = 32; off > 0; off >>= 1) v += __shfl_down(v, off, 64);
    if (j == 0) out[g] = 1.0f / (1.0f + expf(-(v + b2[0])));
}

extern "C" void kernel_launch(void* const* d_in, const int* in_sizes, int n_in,
                              void* d_out, int out_size, void* d_ws, size_t ws_size,
                              hipStream_t stream) {
    const float* mol_x   = (const float*)d_in[0];
    const int*   mol_ei  = (const int*)d_in[1];
    const int*   mol_bat = (const int*)d_in[2];
    const float* prot_x  = (const float*)d_in[3];
    const int*   prot_ei = (const int*)d_in[4];
    const float* gcn_w1  = (const float*)d_in[5];
    const float* gcn_b1  = (const float*)d_in[6];
    const float* gcn_w2  = (const float*)d_in[7];
    const float* gcn_b2  = (const float*)d_in[8];
    const float* gat_w1  = (const float*)d_in[9];
    const float* gat_as1 = (const float*)d_in[10];
    const float* gat_ad1 = (const float*)d_in[11];
    const float* gat_b1  = (const float*)d_in[12];
    const float* gat_w2  = (const float*)d_in[13];
    const float* gat_as2 = (const float*)d_in[14];
    const float* gat_ad2 = (const float*)d_in[15];
    const float* gat_b2  = (const float*)d_in[16];
    const float* cls_w1  = (const float*)d_in[17];
    const float* cls_b1  = (const float*)d_in[18];
    const float* cls_w2  = (const float*)d_in[19];
    const float* cls_b2  = (const float*)d_in[20];
    float* out = (float*)d_out;

    float* ws_f = (float*)d_ws;

    // ---- persistent tail; [gstart .. coarseP+512) is one contiguous zeroed region ----
    float* T       = ws_f + 16777216;
    float* gsum    = T;                       // 262,144 floats (no init needed)
    int*   gstart  = (int*)(T + 262144);      // 4,096 ints (zeroed)
    int*   gend    = (int*)(T + 266240);      // 4,096 ints (zeroed)
    float* psum    = T + 270336;              // 64 floats (zeroed)
    int*   coarseM = (int*)(T + 270400);      // 512 ints (zeroed)
    int*   coarseP = (int*)(T + 270912);      // 512 ints (zeroed)
    int*   cstartM = (int*)(T + 271424);      // 513
    int*   cursorM = (int*)(T + 271937);      // 512
    int*   cstartP = (int*)(T + 272449);      // 513
    int*   cursorP = (int*)(T + 272962);      // 512

    // ---- mol-phase layout ----
    float*    molout = ws_f;                             // [0, 8388608)
    unsigned* bufM   = (unsigned*)ws_f;                  // EM (dead before molout)
    __half*   h2hM   = (__half*)(ws_f + 8388608);        // [8388608, 12582912)
    int*      molCOL = (int*)(ws_f + 12582912);          // EM+64
    int*      molRP  = (int*)(ws_f + 13107264);          // NM
    float*    dinvM  = ws_f + 13238352;                  // NM
    __half*   x8h    = (__half*)(ws_f + 13369440);       // NM*8 halves
    float*    aggM   = ws_f + 13893792;                  // NM*6

    // ---- prot-phase layout (mol fully done first) ----
    float*    protout = ws_f;                            // [0, 6400000)
    unsigned* bufP    = (unsigned*)ws_f;                 // EP (dead before protout)
    __half*   h2hP    = (__half*)(ws_f + 6400000);       // [6400000, 9600000)
    int*      protCOL = (int*)(ws_f + 9600000);          // EP+64
    int*      protRP  = (int*)(ws_f + 11200064);         // NP
    float*    es      = ws_f + 11300080;                 // NP
    float*    ed_     = ws_f + 11400080;                 // NP
    __half*   x32h    = (__half*)(ws_f + 11500080);      // NP*32 halves
    float*    aggP    = ws_f + 13100144;                 // NP*20

    const int KM = 512;   // NM/256
    const int KPb = 391;  // cdiv(NP,256)

    // single upfront zero of gstart+gend+psum+coarseM+coarseP (contiguous)
    (void)hipMemsetAsync(gstart, 0, (size_t)(4096 + 4096 + 64 + 512 + 512) * sizeof(int), stream);

    // ================= mol branch =================
    k_coarse_hist<2048><<<cdiv(EM,2048),256,0,stream>>>(mol_ei + EM, coarseM, EM, KM);
    k_coarse_scan<<<1,512,0,stream>>>(coarseM, cstartM, cursorM, KM, EM);
    k_part<2048,8><<<cdiv(EM,2048),256,0,stream>>>(mol_ei, cursorM, bufM, EM, KM);
    k_fine<20,1><<<KM,256,0,stream>>>(bufM, cstartM, molRP, molCOL, dinvM, NM, KM);
    k_molprep<<<2*cdiv(NM,256),256,0,stream>>>(mol_x, x8h, mol_bat, gstart, gend, NM, cdiv(NM,256));
    k_gather_x8<<<NM/32,256,0,stream>>>(molRP, molCOL, x8h, dinvM, aggM);
    k_mlp<6,0><<<NM/16,256,0,stream>>>(aggM, gcn_w1, gcn_b1, gcn_w2, nullptr, nullptr, h2hM, nullptr, nullptr);
    k_gather64h<0,20><<<NM/4,256,0,stream>>>(molRP, molCOL, h2hM, dinvM, nullptr, nullptr, gcn_b2, molout);
    k_segpool<<<NG,64,0,stream>>>(gstart, gend, molout, gsum);

    // ================= prot branch =================
    k_coarse_hist<4096><<<cdiv(EP,4096),256,0,stream>>>(prot_ei + EP, coarseP, EP, KPb);
    k_coarse_scan<<<1,512,0,stream>>>(coarseP, cstartP, cursorP, KPb, EP);
    k_part<4096,16><<<cdiv(EP,4096),256,0,stream>>>(prot_ei, cursorP, bufP, EP, KPb);
    k_fine<21,0><<<KPb,256,0,stream>>>(bufP, cstartP, protRP, protCOL, nullptr, NP, KPb);
    k_prep_prot<<<cdiv(NP,256),256,0,stream>>>(prot_x, gat_w1, gat_as1, gat_ad1, x32h, es, ed_, NP);
    k_gather_x32<<<NP/4,256,0,stream>>>(protRP, protCOL, x32h, es, ed_, aggP);
    k_mlp<20,1><<<NP/16,256,0,stream>>>(aggP, gat_w1, gat_b1, gat_w2, gat_as2, gat_ad2, h2hP, es, ed_);
    k_gather64h<1,21><<<NP/4,256,0,stream>>>(protRP, protCOL, h2hP, nullptr, es, ed_, gat_b2, protout);
    k_pool_prot<<<1024,256,0,stream>>>(protout, psum, NP);

    // ================= classifier =================
    k_cls<<<NG/4,256,0,stream>>>(gsum, gstart, gend, psum, cls_w1, cls_b1, cls_w2, cls_b2, out);
}

// Round 14
// 473.755 us; speedup vs baseline: 1.1014x; 1.1014x over previous
//
#include <hip/hip_runtime.h>
#include <hip/hip_fp16.h>

#define NM 131072   // mol nodes
#define EM 524288   // mol edges
#define NG 4096     // graphs
#define DM 6        // mol in dim
#define NP 100000   // prot nodes
#define EP 1600000  // prot edges
#define DP 20       // prot in dim

static inline int cdiv(int a, int b){ return (a + b - 1) / b; }

__device__ __forceinline__ float leaky(float x){ return x > 0.f ? x : 0.2f * x; }

union H8 { float4 f4; __half2 h2[4]; };

// ================= bucketed CSR build (round-7, proven) =================
template<int CHUNK>
__global__ void k_coarse_hist(const int* __restrict__ dst, int* __restrict__ coarse,
                              int E, int K){
    __shared__ int lh[512];
    int t = threadIdx.x;
    for (int i = t; i < K; i += 256) lh[i] = 0;
    __syncthreads();
    int base = blockIdx.x * CHUNK;
    int end = min(base + CHUNK, E);
    for (int e = base + t; e < end; e += 256)
        atomicAdd(&lh[dst[e] >> 8], 1);
    __syncthreads();
    for (int i = t; i < K; i += 256)
        if (lh[i]) atomicAdd(&coarse[i], lh[i]);
}

__global__ void k_coarse_scan(const int* __restrict__ coarse, int* __restrict__ cstart,
                              int* __restrict__ cursor, int K, int E){
    int t = threadIdx.x, lane = t & 63, wid = t >> 6;
    int v0 = (t < K) ? coarse[t] : 0;
    int v = v0;
    #pragma unroll
    for (int off = 1; off < 64; off <<= 1) {
        int x = __shfl_up(v, off, 64);
        if (lane >= off) v += x;
    }
    __shared__ int ws[8];
    if (lane == 63) ws[wid] = v;
    __syncthreads();
    int add = 0;
    for (int w = 0; w < wid; w++) add += ws[w];
    int excl = v + add - v0;
    if (t < K) { cstart[t] = excl; cursor[t] = excl; }
    if (t == K - 1) cstart[K] = excl + v0;
}

template<int CHUNK, int EPT>
__global__ void k_part(const int* __restrict__ ei, int* __restrict__ cursor,
                       unsigned* __restrict__ buf, int E, int K){
    __shared__ int lh[512];
    __shared__ int lbase[512];
    int t = threadIdx.x;
    for (int i = t; i < K; i += 256) lh[i] = 0;
    __syncthreads();
    int base = blockIdx.x * CHUNK;
    int end = min(base + CHUNK, E);
    unsigned pay[EPT]; int bslot[EPT];
    int cnt = 0;
    for (int e = base + t; e < end; e += 256) {
        int u = ei[e], v = ei[E + e];
        int b = v >> 8;
        int ls = atomicAdd(&lh[b], 1);
        pay[cnt] = ((unsigned)(v & 255) << 24) | (unsigned)u;
        bslot[cnt] = (b << 13) | ls;
        cnt++;
    }
    __syncthreads();
    for (int i = t; i < K; i += 256)
        lbase[i] = lh[i] ? atomicAdd(&cursor[i], lh[i]) : 0;
    __syncthreads();
    for (int j = 0; j < cnt; j++) {
        int b = bslot[j] >> 13, ls = bslot[j] & 8191;
        buf[lbase[b] + ls] = pay[j];
    }
}

// fine: writes PACKED rp (start | deg<<OBITS) and optionally dinv directly
template<int OBITS, int DINV>
__global__ void k_fine(const unsigned* __restrict__ buf, const int* __restrict__ cstart,
                       int* __restrict__ rp, int* __restrict__ col,
                       float* __restrict__ dinv, int n, int K){
    int k = blockIdx.x, t = threadIdx.x;
    int start = cstart[k], end = cstart[k + 1];
    __shared__ int cnt[256];
    __shared__ int cur[256];
    cnt[t] = 0;
    __syncthreads();
    for (int p = start + t; p < end; p += 256)
        atomicAdd(&cnt[buf[p] >> 24], 1);
    __syncthreads();
    int v0 = cnt[t];
    int lane = t & 63, wid = t >> 6;
    int v = v0;
    #pragma unroll
    for (int off = 1; off < 64; off <<= 1) {
        int x = __shfl_up(v, off, 64);
        if (lane >= off) v += x;
    }
    __shared__ int ws[4];
    if (lane == 63) ws[wid] = v;
    __syncthreads();
    int add = 0;
    for (int w = 0; w < wid; w++) add += ws[w];
    int excl = v + add - v0;
    int ofs = start + excl;
    cur[t] = ofs;
    int idx = (k << 8) + t;
    if (idx < n) {
        rp[idx] = (int)((unsigned)ofs | ((unsigned)v0 << OBITS));
        if (DINV) dinv[idx] = rsqrtf((float)(v0 + 1));
    }
    __syncthreads();
    for (int p = start + t; p < end; p += 256) {
        unsigned pk = buf[p];
        int slot = atomicAdd(&cur[pk >> 24], 1);
        col[slot] = (int)(pk & 0xFFFFFFu);
    }
}

// ---------------- fused: mol x -> dinv-prescaled 8-half rows + segment bounds ----------------
__global__ void k_molprep(const float* __restrict__ x, const float* __restrict__ dinv,
                          __half* __restrict__ x8, const int* __restrict__ batch,
                          int* __restrict__ gstart, int* __restrict__ gend, int n, int nbA){
    int b = blockIdx.x;
    if (b < nbA) {
        int i = b * 256 + threadIdx.x;
        if (i >= n) return;
        float dd = dinv[i];
        H8 r;
        #pragma unroll
        for (int k = 0; k < 3; k++)
            r.h2[k] = __floats2half2_rn(dd * x[i*6 + 2*k], dd * x[i*6 + 2*k + 1]);
        r.h2[3] = __floats2half2_rn(0.f, 0.f);
        *(float4*)&x8[(size_t)i * 8] = r.f4;
    } else {
        int i = (b - nbA) * 256 + threadIdx.x;
        if (i >= n) return;
        int g = batch[i];
        if (i == 0 || batch[i - 1] != g) gstart[g] = i;
        if (i == n - 1 || batch[i + 1] != g) gend[g] = i + 1;
    }
}

// ---------------- prep: prot x -> padded 32-half rows + es/ed dots ----------------
__global__ void k_prep_prot(const float* __restrict__ x, const float* __restrict__ W1,
                            const float* __restrict__ as_, const float* __restrict__ ad_,
                            __half* __restrict__ x32, float* __restrict__ es,
                            float* __restrict__ ed_, int n){
    __shared__ float vas[20], vds[20];
    int t = threadIdx.x;
    if (t < 20) {
        float s = 0.f;
        for (int j = 0; j < 64; j++) s += W1[t * 64 + j] * as_[j];
        vas[t] = s;
    } else if (t >= 32 && t < 52) {
        int k = t - 32;
        float s = 0.f;
        for (int j = 0; j < 64; j++) s += W1[k * 64 + j] * ad_[j];
        vds[k] = s;
    }
    __syncthreads();
    int i = blockIdx.x * 256 + t;
    if (i >= n) return;
    float xv[20];
    float s = 0.f, d = 0.f;
    #pragma unroll
    for (int k = 0; k < 20; k++) {
        xv[k] = x[i*20 + k];
        s += xv[k] * vas[k]; d += xv[k] * vds[k];
    }
    es[i] = s; ed_[i] = d;
    H8 r0, r1, r2, rz;
    #pragma unroll
    for (int k = 0; k < 4; k++) r0.h2[k] = __floats2half2_rn(xv[2*k],   xv[2*k+1]);
    #pragma unroll
    for (int k = 0; k < 4; k++) r1.h2[k] = __floats2half2_rn(xv[8+2*k], xv[9+2*k]);
    r2.h2[0] = __floats2half2_rn(xv[16], xv[17]);
    r2.h2[1] = __floats2half2_rn(xv[18], xv[19]);
    r2.h2[2] = __floats2half2_rn(0.f, 0.f);
    r2.h2[3] = __floats2half2_rn(0.f, 0.f);
    rz.h2[0] = rz.h2[1] = rz.h2[2] = rz.h2[3] = __floats2half2_rn(0.f, 0.f);
    *(float4*)&x32[(size_t)i * 32]      = r0.f4;
    *(float4*)&x32[(size_t)i * 32 + 8]  = r1.f4;
    *(float4*)&x32[(size_t)i * 32 + 16] = r2.f4;
    *(float4*)&x32[(size_t)i * 32 + 24] = rz.f4;
}

// ---------------- mol L1 gather: 8 lanes/node, 8 nodes/wave, pre-scaled rows ----------------
__global__ void k_gather_x8(const int* __restrict__ rp, const int* __restrict__ col,
                            const __half* __restrict__ x8, const float* __restrict__ dinv,
                            float* __restrict__ agg){
    __shared__ float ost[192];
    int tid = threadIdx.x;
    int wv = tid >> 6, l = tid & 63, g = l >> 3, q = l & 7;
    int node = (blockIdx.x << 5) + (wv << 3) + g;
    unsigned pk = (unsigned)rp[node];
    int s0 = (int)(pk & 0xFFFFFu);
    int deg = (int)(pk >> 20);
    float acc[6] = {0.f,0.f,0.f,0.f,0.f,0.f};
    if (q == 0) {   // self row (already dinv-scaled)
        H8 r; r.f4 = *(const float4*)&x8[(size_t)node * 8];
        #pragma unroll
        for (int i = 0; i < 3; i++) {
            float2 f = __half22float2(r.h2[i]);
            acc[2*i] = f.x; acc[2*i+1] = f.y;
        }
    }
    for (int base = 0; base < deg; base += 8) {
        int s = base + q;
        int c = col[s0 + s];
        int u = (s < deg) ? c : node;
        float wvv = (s < deg) ? 1.f : 0.f;
        H8 r; r.f4 = *(const float4*)&x8[(size_t)u * 8];
        #pragma unroll
        for (int i = 0; i < 3; i++) {
            float2 f = __half22float2(r.h2[i]);
            acc[2*i] += wvv * f.x; acc[2*i+1] += wvv * f.y;
        }
    }
    #pragma unroll
    for (int m = 1; m < 8; m <<= 1) {
        #pragma unroll
        for (int i = 0; i < 6; i++) acc[i] += __shfl_xor(acc[i], m, 8);
    }
    if (q == 0) {
        float dd = dinv[node];
        int slot = (wv << 3) + g;
        #pragma unroll
        for (int i = 0; i < 6; i++) ost[slot * 6 + i] = dd * acc[i];
    }
    __syncthreads();
    if (tid < 48)
        *(float4*)&agg[(size_t)blockIdx.x * 192 + (tid << 2)] = *(float4*)&ost[tid << 2];
}

// ---------------- prot L1 GAT gather: 16 slots x 4 lanes, inline exp weights ----------------
__global__ void k_gather_x32(const int* __restrict__ rp, const int* __restrict__ col,
                             const __half* __restrict__ x32, const float* __restrict__ es,
                             const float* __restrict__ ed_, float* __restrict__ agg){
    int tid = threadIdx.x;
    int node = (blockIdx.x << 2) + (tid >> 6);
    int l = tid & 63, g = l >> 2, q = l & 3;
    unsigned pk = (unsigned)rp[node];
    int s0 = (int)(pk & 0x1FFFFFu);
    int deg = (int)(pk >> 21);
    float edv = ed_[node];
    float selfw = __expf(leaky(es[node] + edv));
    float acc[8] = {0.f,0.f,0.f,0.f,0.f,0.f,0.f,0.f};
    float den = (l == 0) ? selfw : 0.f;
    if (g == 0 && q < 3) {
        H8 r; r.f4 = *(const float4*)&x32[(size_t)node * 32 + (q << 3)];
        #pragma unroll
        for (int i = 0; i < 4; i++) {
            float2 f = __half22float2(r.h2[i]);
            acc[2*i] = selfw * f.x; acc[2*i+1] = selfw * f.y;
        }
    }
    for (int base = 0; base < deg; base += 16) {
        int s = base + g;
        int c = col[s0 + s];
        int u = (s < deg) ? c : node;
        float wvv = (s < deg) ? __expf(leaky(es[u] + edv)) : 0.f;
        if (q < 3) {
            H8 r; r.f4 = *(const float4*)&x32[(size_t)u * 32 + (q << 3)];
            #pragma unroll
            for (int i = 0; i < 4; i++) {
                float2 f = __half22float2(r.h2[i]);
                acc[2*i] += wvv * f.x; acc[2*i+1] += wvv * f.y;
            }
        }
        if (q == 0) den += wvv;
    }
    #pragma unroll
    for (int m = 4; m <= 32; m <<= 1) {
        #pragma unroll
        for (int i = 0; i < 8; i++) acc[i] += __shfl_xor(acc[i], m, 64);
        den += __shfl_xor(den, m, 64);
    }
    den = __shfl(den, 0, 64);
    float inv = 1.f / den;
    if (g == 0) {
        if (q < 2) {
            float4 v0 = make_float4(acc[0]*inv, acc[1]*inv, acc[2]*inv, acc[3]*inv);
            float4 v1 = make_float4(acc[4]*inv, acc[5]*inv, acc[6]*inv, acc[7]*inv);
            *(float4*)&agg[(size_t)node * 20 + (q << 3)]     = v0;
            *(float4*)&agg[(size_t)node * 20 + (q << 3) + 4] = v1;
        } else if (q == 2) {
            float4 v0 = make_float4(acc[0]*inv, acc[1]*inv, acc[2]*inv, acc[3]*inv);
            *(float4*)&agg[(size_t)node * 20 + 16] = v0;
        }
    }
}

// ---------------- fused MLP: agg @ W1 + b1 -> relu -> @ W2 -> fp16 (+att dots / dinv scale) ----------------
template<int D, int ATT, int SCALE>
__global__ void k_mlp(const float* __restrict__ agg, const float* __restrict__ W1,
                      const float* __restrict__ b1, const float* __restrict__ W2,
                      const float* __restrict__ as_, const float* __restrict__ ad_,
                      __half* __restrict__ hout, float* __restrict__ es,
                      float* __restrict__ ed_, const float* __restrict__ dinv){
    __shared__ float W1s[D * 64];
    __shared__ float W2s[64 * 64];
    __shared__ float A[16][D + 1];
    __shared__ float X1[16][68];
    int tid = threadIdx.x;
    for (int k = tid; k < D * 64; k += 256) W1s[k] = W1[k];
    for (int k = tid * 4; k < 4096; k += 1024)
        *(float4*)&W2s[k] = *(const float4*)&W2[k];
    int nd = tid >> 4, q = tid & 15;
    size_t node = (size_t)blockIdx.x * 16 + nd;
    for (int k = q; k < D; k += 16) A[nd][k] = agg[node * D + k];
    __syncthreads();
    float4 h1 = *(const float4*)&b1[q << 2];
    #pragma unroll
    for (int k = 0; k < D; k++) {
        float xk = A[nd][k];
        float4 w4 = *(const float4*)&W1s[(k << 6) + (q << 2)];
        h1.x += xk * w4.x; h1.y += xk * w4.y; h1.z += xk * w4.z; h1.w += xk * w4.w;
    }
    h1.x = fmaxf(h1.x, 0.f); h1.y = fmaxf(h1.y, 0.f);
    h1.z = fmaxf(h1.z, 0.f); h1.w = fmaxf(h1.w, 0.f);
    *(float4*)&X1[nd][q << 2] = h1;
    __syncthreads();
    float4 acc = {0.f, 0.f, 0.f, 0.f};
    #pragma unroll 8
    for (int k = 0; k < 64; k++) {
        float xk = X1[nd][k];
        float4 w4 = *(const float4*)&W2s[(k << 6) + (q << 2)];
        acc.x += xk * w4.x; acc.y += xk * w4.y; acc.z += xk * w4.z; acc.w += xk * w4.w;
    }
    float4 st = acc;
    if (SCALE) {
        float dd = dinv[node];
        st.x *= dd; st.y *= dd; st.z *= dd; st.w *= dd;
    }
    union { __half2 h2[2]; float2 f2; } u;
    u.h2[0] = __floats2half2_rn(st.x, st.y);
    u.h2[1] = __floats2half2_rn(st.z, st.w);
    *(float2*)&hout[node * 64 + (q << 2)] = u.f2;
    if (ATT) {
        int f = q << 2;
        float xa = acc.x * as_[f] + acc.y * as_[f + 1] + acc.z * as_[f + 2] + acc.w * as_[f + 3];
        float ya = acc.x * ad_[f] + acc.y * ad_[f + 1] + acc.z * ad_[f + 2] + acc.w * ad_[f + 3];
        #pragma unroll
        for (int m = 1; m < 16; m <<= 1) {
            xa += __shfl_xor(xa, m, 16);
            ya += __shfl_xor(ya, m, 16);
        }
        if (q == 0) { es[node] = xa; ed_[node] = ya; }
    }
}

// ---------------- mol layer-2 gather: 8 slots x 8 lanes, pre-scaled rows ----------------
__global__ void k_gather64h_gcn(const int* __restrict__ rp, const int* __restrict__ col,
                                const __half* __restrict__ hh, const float* __restrict__ dinv,
                                const float* __restrict__ b, float* __restrict__ out){
    int tid = threadIdx.x;
    int node = (blockIdx.x << 2) + (tid >> 6);
    int l = tid & 63, g = l >> 3, q = l & 7;
    unsigned pk = (unsigned)rp[node];
    int s0 = (int)(pk & 0xFFFFFu);
    int deg = (int)(pk >> 20);
    float acc[8] = {0.f,0.f,0.f,0.f,0.f,0.f,0.f,0.f};
    if (g == 0) {   // self row (pre-scaled by dinv[node])
        H8 r; r.f4 = *(const float4*)&hh[(size_t)node * 64 + (q << 3)];
        #pragma unroll
        for (int i = 0; i < 4; i++) {
            float2 f = __half22float2(r.h2[i]);
            acc[2*i]     = f.x;
            acc[2*i + 1] = f.y;
        }
    }
    for (int base = 0; base < deg; base += 8) {
        int s = base + g;
        int c = col[s0 + s];
        int u = (s < deg) ? c : node;
        float wvv = (s < deg) ? 1.f : 0.f;
        H8 r; r.f4 = *(const float4*)&hh[(size_t)u * 64 + (q << 3)];
        #pragma unroll
        for (int i = 0; i < 4; i++) {
            float2 f = __half22float2(r.h2[i]);
            acc[2*i]     += wvv * f.x;
            acc[2*i + 1] += wvv * f.y;
        }
    }
    #pragma unroll
    for (int m = 8; m <= 32; m <<= 1) {
        #pragma unroll
        for (int i = 0; i < 8; i++) acc[i] += __shfl_xor(acc[i], m, 64);
    }
    if (g == 0) {
        float sc = dinv[node];
        int f = q << 3;
        float4 v0, v1;
        v0.x = acc[0]*sc + b[f];     v0.y = acc[1]*sc + b[f+1];
        v0.z = acc[2]*sc + b[f+2];   v0.w = acc[3]*sc + b[f+3];
        v1.x = acc[4]*sc + b[f+4];   v1.y = acc[5]*sc + b[f+5];
        v1.z = acc[6]*sc + b[f+6];   v1.w = acc[7]*sc + b[f+7];
        *(float4*)&out[(size_t)node * 64 + f]     = v0;
        *(float4*)&out[(size_t)node * 64 + f + 4] = v1;
    }
}

// ---------------- prot layer-2 gather: 16 slots x 4 lanes x 32 B, inline exp ----------------
__global__ void k_gather64h_gat(const int* __restrict__ rp, const int* __restrict__ col,
                                const __half* __restrict__ hh, const float* __restrict__ es,
                                const float* __restrict__ ed_, const float* __restrict__ b,
                                float* __restrict__ out){
    int tid = threadIdx.x;
    int node = (blockIdx.x << 2) + (tid >> 6);
    int l = tid & 63, g = l >> 2, q = l & 3;
    unsigned pk = (unsigned)rp[node];
    int s0 = (int)(pk & 0x1FFFFFu);
    int deg = (int)(pk >> 21);
    float edv = ed_[node];
    float selfw = __expf(leaky(es[node] + edv));
    float acc[16];
    #pragma unroll
    for (int i = 0; i < 16; i++) acc[i] = 0.f;
    float den = (l == 0) ? selfw : 0.f;
    if (g == 0) {
        H8 r0, r1;
        r0.f4 = *(const float4*)&hh[(size_t)node * 64 + (q << 4)];
        r1.f4 = *(const float4*)&hh[(size_t)node * 64 + (q << 4) + 8];
        #pragma unroll
        for (int i = 0; i < 4; i++) {
            float2 f0 = __half22float2(r0.h2[i]);
            float2 f1 = __half22float2(r1.h2[i]);
            acc[2*i]     = selfw * f0.x; acc[2*i+1]   = selfw * f0.y;
            acc[8+2*i]   = selfw * f1.x; acc[8+2*i+1] = selfw * f1.y;
        }
    }
    for (int base = 0; base < deg; base += 16) {
        int s = base + g;
        int c = col[s0 + s];
        int u = (s < deg) ? c : node;
        float wvv = (s < deg) ? __expf(leaky(es[u] + edv)) : 0.f;
        H8 r0, r1;
        r0.f4 = *(const float4*)&hh[(size_t)u * 64 + (q << 4)];
        r1.f4 = *(const float4*)&hh[(size_t)u * 64 + (q << 4) + 8];
        #pragma unroll
        for (int i = 0; i < 4; i++) {
            float2 f0 = __half22float2(r0.h2[i]);
            float2 f1 = __half22float2(r1.h2[i]);
            acc[2*i]     += wvv * f0.x; acc[2*i+1]   += wvv * f0.y;
            acc[8+2*i]   += wvv * f1.x; acc[8+2*i+1] += wvv * f1.y;
        }
        if (q == 0) den += wvv;
    }
    #pragma unroll
    for (int m = 4; m <= 32; m <<= 1) {
        #pragma unroll
        for (int i = 0; i < 16; i++) acc[i] += __shfl_xor(acc[i], m, 64);
        den += __shfl_xor(den, m, 64);
    }
    den = __shfl(den, 0, 64);
    if (g == 0) {
        float sc = 1.f / den;
        int f = q << 4;
        #pragma unroll
        for (int c4 = 0; c4 < 4; c4++) {
            float4 v;
            v.x = acc[4*c4]   * sc + b[f + 4*c4];
            v.y = acc[4*c4+1] * sc + b[f + 4*c4 + 1];
            v.z = acc[4*c4+2] * sc + b[f + 4*c4 + 2];
            v.w = acc[4*c4+3] * sc + b[f + 4*c4 + 3];
            *(float4*)&out[(size_t)node * 64 + f + 4*c4] = v;
        }
    }
}

// ---------------- mol pooling ----------------
__global__ void k_segpool(const int* __restrict__ gstart, const int* __restrict__ gend,
                          const float* __restrict__ x, float* __restrict__ gsum){
    int gph = blockIdx.x, t = threadIdx.x;
    int rg = t >> 4, q = t & 15;
    int s = gstart[gph], c = gend[gph] - gstart[gph];
    float4 a = {0.f, 0.f, 0.f, 0.f};
    for (int i = rg; i < c; i += 4) {
        float4 v = *(const float4*)&x[(size_t)(s + i) * 64 + (q << 2)];
        a.x += v.x; a.y += v.y; a.z += v.z; a.w += v.w;
    }
    #pragma unroll
    for (int m = 16; m <= 32; m <<= 1) {
        a.x += __shfl_xor(a.x, m, 64);
        a.y += __shfl_xor(a.y, m, 64);
        a.z += __shfl_xor(a.z, m, 64);
        a.w += __shfl_xor(a.w, m, 64);
    }
    if (rg == 0) *(float4*)&gsum[gph * 64 + (q << 2)] = a;
}

// ---------------- prot pooling ----------------
__global__ void k_pool_prot(const float* __restrict__ x, float* __restrict__ psum, int n){
    __shared__ float red[4][64];
    int t = threadIdx.x, lane = t & 63, wv = t >> 6;
    const float4* x4 = (const float4*)x;
    int total = n * 16;
    float4 a = {0.f, 0.f, 0.f, 0.f};
    for (int i = blockIdx.x * 256 + t; i < total; i += gridDim.x * 256) {
        float4 v = x4[i];
        a.x += v.x; a.y += v.y; a.z += v.z; a.w += v.w;
    }
    #pragma unroll
    for (int m = 16; m <= 32; m <<= 1) {
        a.x += __shfl_xor(a.x, m, 64);
        a.y += __shfl_xor(a.y, m, 64);
        a.z += __shfl_xor(a.z, m, 64);
        a.w += __shfl_xor(a.w, m, 64);
    }
    if (lane < 16) *(float4*)&red[wv][lane << 2] = a;
    __syncthreads();
    if (t < 64) {
        float s = red[0][t] + red[1][t] + red[2][t] + red[3][t];
        atomicAdd(&psum[t], s);
    }
}

// ---------------- fused classifier ----------------
__global__ void k_cls(const float* __restrict__ gsum, const int* __restrict__ gstart,
                      const int* __restrict__ gend, const float* __restrict__ psum,
                      const float* __restrict__ W1, const float* __restrict__ b1,
                      const float* __restrict__ w2, const float* __restrict__ b2,
                      float* __restrict__ out){
    __shared__ float W1s[128 * 64];
    int tid = threadIdx.x;
    for (int k = tid; k < 128 * 64; k += 256) W1s[k] = W1[k];
    __syncthreads();
    int g = blockIdx.x * 4 + (tid >> 6);
    int j = tid & 63;
    float cntf = (float)(gend[g] - gstart[g]);
    float inv = 1.0f / fmaxf(cntf, 1.0f);
    const float invp = 1.0f / (float)NP;
    float acc = b1[j];
    #pragma unroll 8
    for (int k = 0; k < 64; k++) acc += (gsum[g * 64 + k] * inv) * W1s[k * 64 + j];
    #pragma unroll 8
    for (int k = 0; k < 64; k++) acc += (psum[k] * invp) * W1s[(64 + k) * 64 + j];
    float v = fmaxf(acc, 0.f) * w2[j];
    #pragma unroll
    for (int off = 32; off > 0; off >>= 1) v += __shfl_down(v, off, 64);
    if (j == 0) out[g] = 1.0f / (1.0f + expf(-(v + b2[0])));
}

extern "C" void kernel_launch(void* const* d_in, const int* in_sizes, int n_in,
                              void* d_out, int out_size, void* d_ws, size_t ws_size,
                              hipStream_t stream) {
    const float* mol_x   = (const float*)d_in[0];
    const int*   mol_ei  = (const int*)d_in[1];
    const int*   mol_bat = (const int*)d_in[2];
    const float* prot_x  = (const float*)d_in[3];
    const int*   prot_ei = (const int*)d_in[4];
    const float* gcn_w1  = (const float*)d_in[5];
    const float* gcn_b1  = (const float*)d_in[6];
    const float* gcn_w2  = (const float*)d_in[7];
    const float* gcn_b2  = (const float*)d_in[8];
    const float* gat_w1  = (const float*)d_in[9];
    const float* gat_as1 = (const float*)d_in[10];
    const float* gat_ad1 = (const float*)d_in[11];
    const float* gat_b1  = (const float*)d_in[12];
    const float* gat_w2  = (const float*)d_in[13];
    const float* gat_as2 = (const float*)d_in[14];
    const float* gat_ad2 = (const float*)d_in[15];
    const float* gat_b2  = (const float*)d_in[16];
    const float* cls_w1  = (const float*)d_in[17];
    const float* cls_b1  = (const float*)d_in[18];
    const float* cls_w2  = (const float*)d_in[19];
    const float* cls_b2  = (const float*)d_in[20];
    float* out = (float*)d_out;

    float* ws_f = (float*)d_ws;

    // ---- persistent tail; [gstart .. coarseP+512) is one contiguous zeroed region ----
    float* T       = ws_f + 16777216;
    float* gsum    = T;                       // 262,144 floats (no init needed)
    int*   gstart  = (int*)(T + 262144);      // 4,096 ints (zeroed)
    int*   gend    = (int*)(T + 266240);      // 4,096 ints (zeroed)
    float* psum    = T + 270336;              // 64 floats (zeroed)
    int*   coarseM = (int*)(T + 270400);      // 512 ints (zeroed)
    int*   coarseP = (int*)(T + 270912);      // 512 ints (zeroed)
    int*   cstartM = (int*)(T + 271424);      // 513
    int*   cursorM = (int*)(T + 271937);      // 512
    int*   cstartP = (int*)(T + 272449);      // 513
    int*   cursorP = (int*)(T + 272962);      // 512

    // ---- mol-phase layout ----
    float*    molout = ws_f;                             // [0, 8388608)
    unsigned* bufM   = (unsigned*)ws_f;                  // EM (dead before molout)
    __half*   h2hM   = (__half*)(ws_f + 8388608);        // [8388608, 12582912)
    int*      molCOL = (int*)(ws_f + 12582912);          // EM+64
    int*      molRP  = (int*)(ws_f + 13107264);          // NM
    float*    dinvM  = ws_f + 13238352;                  // NM
    __half*   x8h    = (__half*)(ws_f + 13369440);       // NM*8 halves
    float*    aggM   = ws_f + 13893792;                  // NM*6

    // ---- prot-phase layout (mol fully done first) ----
    float*    protout = ws_f;                            // [0, 6400000)
    unsigned* bufP    = (unsigned*)ws_f;                 // EP (dead before protout)
    __half*   h2hP    = (__half*)(ws_f + 6400000);       // [6400000, 9600000)
    int*      protCOL = (int*)(ws_f + 9600000);          // EP+64
    int*      protRP  = (int*)(ws_f + 11200064);         // NP
    float*    es      = ws_f + 11300080;                 // NP
    float*    ed_     = ws_f + 11400080;                 // NP
    __half*   x32h    = (__half*)(ws_f + 11500080);      // NP*32 halves
    float*    aggP    = ws_f + 13100144;                 // NP*20

    const int KM = 512;   // NM/256
    const int KPb = 391;  // cdiv(NP,256)

    // single upfront zero of gstart+gend+psum+coarseM+coarseP (contiguous)
    (void)hipMemsetAsync(gstart, 0, (size_t)(4096 + 4096 + 64 + 512 + 512) * sizeof(int), stream);

    // ================= mol branch =================
    k_coarse_hist<2048><<<cdiv(EM,2048),256,0,stream>>>(mol_ei + EM, coarseM, EM, KM);
    k_coarse_scan<<<1,512,0,stream>>>(coarseM, cstartM, cursorM, KM, EM);
    k_part<2048,8><<<cdiv(EM,2048),256,0,stream>>>(mol_ei, cursorM, bufM, EM, KM);
    k_fine<20,1><<<KM,256,0,stream>>>(bufM, cstartM, molRP, molCOL, dinvM, NM, KM);
    k_molprep<<<2*cdiv(NM,256),256,0,stream>>>(mol_x, dinvM, x8h, mol_bat, gstart, gend, NM, cdiv(NM,256));
    k_gather_x8<<<NM/32,256,0,stream>>>(molRP, molCOL, x8h, dinvM, aggM);
    k_mlp<6,0,1><<<NM/16,256,0,stream>>>(aggM, gcn_w1, gcn_b1, gcn_w2, nullptr, nullptr, h2hM, nullptr, nullptr, dinvM);
    k_gather64h_gcn<<<NM/4,256,0,stream>>>(molRP, molCOL, h2hM, dinvM, gcn_b2, molout);
    k_segpool<<<NG,64,0,stream>>>(gstart, gend, molout, gsum);

    // ================= prot branch =================
    k_coarse_hist<4096><<<cdiv(EP,4096),256,0,stream>>>(prot_ei + EP, coarseP, EP, KPb);
    k_coarse_scan<<<1,512,0,stream>>>(coarseP, cstartP, cursorP, KPb, EP);
    k_part<4096,16><<<cdiv(EP,4096),256,0,stream>>>(prot_ei, cursorP, bufP, EP, KPb);
    k_fine<21,0><<<KPb,256,0,stream>>>(bufP, cstartP, protRP, protCOL, nullptr, NP, KPb);
    k_prep_prot<<<cdiv(NP,256),256,0,stream>>>(prot_x, gat_w1, gat_as1, gat_ad1, x32h, es, ed_, NP);
    k_gather_x32<<<NP/4,256,0,stream>>>(protRP, protCOL, x32h, es, ed_, aggP);
    k_mlp<20,1,0><<<NP/16,256,0,stream>>>(aggP, gat_w1, gat_b1, gat_w2, gat_as2, gat_ad2, h2hP, es, ed_, nullptr);
    k_gather64h_gat<<<NP/4,256,0,stream>>>(protRP, protCOL, h2hP, es, ed_, gat_b2, protout);
    k_pool_prot<<<1024,256,0,stream>>>(protout, psum, NP);

    // ================= classifier =================
    k_cls<<<NG/4,256,0,stream>>>(gsum, gstart, gend, psum, cls_w1, cls_b1, cls_w2, cls_b2, out);
}

// Round 15
// 447.442 us; speedup vs baseline: 1.1662x; 1.0588x over previous
//
#include <hip/hip_runtime.h>
#include <hip/hip_fp16.h>

#define NM 131072   // mol nodes
#define EM 524288   // mol edges
#define NG 4096     // graphs
#define DM 6        // mol in dim
#define NP 100000   // prot nodes
#define EP 1600000  // prot edges
#define DP 20       // prot in dim

static inline int cdiv(int a, int b){ return (a + b - 1) / b; }

__device__ __forceinline__ float leaky(float x){ return x > 0.f ? x : 0.2f * x; }

union H8 { float4 f4; __half2 h2[4]; };

// ================= bucketed CSR build (round-7, proven) =================
template<int CHUNK>
__global__ void k_coarse_hist(const int* __restrict__ dst, int* __restrict__ coarse,
                              int E, int K){
    __shared__ int lh[512];
    int t = threadIdx.x;
    for (int i = t; i < K; i += 256) lh[i] = 0;
    __syncthreads();
    int base = blockIdx.x * CHUNK;
    int end = min(base + CHUNK, E);
    for (int e = base + t; e < end; e += 256)
        atomicAdd(&lh[dst[e] >> 8], 1);
    __syncthreads();
    for (int i = t; i < K; i += 256)
        if (lh[i]) atomicAdd(&coarse[i], lh[i]);
}

__global__ void k_coarse_scan(const int* __restrict__ coarse, int* __restrict__ cstart,
                              int* __restrict__ cursor, int K, int E){
    int t = threadIdx.x, lane = t & 63, wid = t >> 6;
    int v0 = (t < K) ? coarse[t] : 0;
    int v = v0;
    #pragma unroll
    for (int off = 1; off < 64; off <<= 1) {
        int x = __shfl_up(v, off, 64);
        if (lane >= off) v += x;
    }
    __shared__ int ws[8];
    if (lane == 63) ws[wid] = v;
    __syncthreads();
    int add = 0;
    for (int w = 0; w < wid; w++) add += ws[w];
    int excl = v + add - v0;
    if (t < K) { cstart[t] = excl; cursor[t] = excl; }
    if (t == K - 1) cstart[K] = excl + v0;
}

template<int CHUNK, int EPT>
__global__ void k_part(const int* __restrict__ ei, int* __restrict__ cursor,
                       unsigned* __restrict__ buf, int E, int K){
    __shared__ int lh[512];
    __shared__ int lbase[512];
    int t = threadIdx.x;
    for (int i = t; i < K; i += 256) lh[i] = 0;
    __syncthreads();
    int base = blockIdx.x * CHUNK;
    int end = min(base + CHUNK, E);
    unsigned pay[EPT]; int bslot[EPT];
    int cnt = 0;
    for (int e = base + t; e < end; e += 256) {
        int u = ei[e], v = ei[E + e];
        int b = v >> 8;
        int ls = atomicAdd(&lh[b], 1);
        pay[cnt] = ((unsigned)(v & 255) << 24) | (unsigned)u;
        bslot[cnt] = (b << 13) | ls;
        cnt++;
    }
    __syncthreads();
    for (int i = t; i < K; i += 256)
        lbase[i] = lh[i] ? atomicAdd(&cursor[i], lh[i]) : 0;
    __syncthreads();
    for (int j = 0; j < cnt; j++) {
        int b = bslot[j] >> 13, ls = bslot[j] & 8191;
        buf[lbase[b] + ls] = pay[j];
    }
}

// fine: writes PACKED rp (start | deg<<OBITS) and optionally dinv directly
template<int OBITS, int DINV>
__global__ void k_fine(const unsigned* __restrict__ buf, const int* __restrict__ cstart,
                       int* __restrict__ rp, int* __restrict__ col,
                       float* __restrict__ dinv, int n, int K){
    int k = blockIdx.x, t = threadIdx.x;
    int start = cstart[k], end = cstart[k + 1];
    __shared__ int cnt[256];
    __shared__ int cur[256];
    cnt[t] = 0;
    __syncthreads();
    for (int p = start + t; p < end; p += 256)
        atomicAdd(&cnt[buf[p] >> 24], 1);
    __syncthreads();
    int v0 = cnt[t];
    int lane = t & 63, wid = t >> 6;
    int v = v0;
    #pragma unroll
    for (int off = 1; off < 64; off <<= 1) {
        int x = __shfl_up(v, off, 64);
        if (lane >= off) v += x;
    }
    __shared__ int ws[4];
    if (lane == 63) ws[wid] = v;
    __syncthreads();
    int add = 0;
    for (int w = 0; w < wid; w++) add += ws[w];
    int excl = v + add - v0;
    int ofs = start + excl;
    cur[t] = ofs;
    int idx = (k << 8) + t;
    if (idx < n) {
        rp[idx] = (int)((unsigned)ofs | ((unsigned)v0 << OBITS));
        if (DINV) dinv[idx] = rsqrtf((float)(v0 + 1));
    }
    __syncthreads();
    for (int p = start + t; p < end; p += 256) {
        unsigned pk = buf[p];
        int slot = atomicAdd(&cur[pk >> 24], 1);
        col[slot] = (int)(pk & 0xFFFFFFu);
    }
}

// ---------------- fused: mol x -> dinv-prescaled 8-half rows + segment bounds ----------------
__global__ void k_molprep(const float* __restrict__ x, const float* __restrict__ dinv,
                          __half* __restrict__ x8, const int* __restrict__ batch,
                          int* __restrict__ gstart, int* __restrict__ gend, int n, int nbA){
    int b = blockIdx.x;
    if (b < nbA) {
        int i = b * 256 + threadIdx.x;
        if (i >= n) return;
        float dd = dinv[i];
        H8 r;
        #pragma unroll
        for (int k = 0; k < 3; k++)
            r.h2[k] = __floats2half2_rn(dd * x[i*6 + 2*k], dd * x[i*6 + 2*k + 1]);
        r.h2[3] = __floats2half2_rn(0.f, 0.f);
        *(float4*)&x8[(size_t)i * 8] = r.f4;
    } else {
        int i = (b - nbA) * 256 + threadIdx.x;
        if (i >= n) return;
        int g = batch[i];
        if (i == 0 || batch[i - 1] != g) gstart[g] = i;
        if (i == n - 1 || batch[i + 1] != g) gend[g] = i + 1;
    }
}

// ---------------- prep: prot x -> padded 32-half rows + es/ed dots ----------------
__global__ void k_prep_prot(const float* __restrict__ x, const float* __restrict__ W1,
                            const float* __restrict__ as_, const float* __restrict__ ad_,
                            __half* __restrict__ x32, float* __restrict__ es,
                            float* __restrict__ ed_, int n){
    __shared__ float vas[20], vds[20];
    int t = threadIdx.x;
    if (t < 20) {
        float s = 0.f;
        for (int j = 0; j < 64; j++) s += W1[t * 64 + j] * as_[j];
        vas[t] = s;
    } else if (t >= 32 && t < 52) {
        int k = t - 32;
        float s = 0.f;
        for (int j = 0; j < 64; j++) s += W1[k * 64 + j] * ad_[j];
        vds[k] = s;
    }
    __syncthreads();
    int i = blockIdx.x * 256 + t;
    if (i >= n) return;
    float xv[20];
    float s = 0.f, d = 0.f;
    #pragma unroll
    for (int k = 0; k < 20; k++) {
        xv[k] = x[i*20 + k];
        s += xv[k] * vas[k]; d += xv[k] * vds[k];
    }
    es[i] = s; ed_[i] = d;
    H8 r0, r1, r2, rz;
    #pragma unroll
    for (int k = 0; k < 4; k++) r0.h2[k] = __floats2half2_rn(xv[2*k],   xv[2*k+1]);
    #pragma unroll
    for (int k = 0; k < 4; k++) r1.h2[k] = __floats2half2_rn(xv[8+2*k], xv[9+2*k]);
    r2.h2[0] = __floats2half2_rn(xv[16], xv[17]);
    r2.h2[1] = __floats2half2_rn(xv[18], xv[19]);
    r2.h2[2] = __floats2half2_rn(0.f, 0.f);
    r2.h2[3] = __floats2half2_rn(0.f, 0.f);
    rz.h2[0] = rz.h2[1] = rz.h2[2] = rz.h2[3] = __floats2half2_rn(0.f, 0.f);
    *(float4*)&x32[(size_t)i * 32]      = r0.f4;
    *(float4*)&x32[(size_t)i * 32 + 8]  = r1.f4;
    *(float4*)&x32[(size_t)i * 32 + 16] = r2.f4;
    *(float4*)&x32[(size_t)i * 32 + 24] = rz.f4;
}

// ---------------- mol L1 gather: 8 lanes/node, 8 nodes/wave, pre-scaled rows ----------------
__global__ void k_gather_x8(const int* __restrict__ rp, const int* __restrict__ col,
                            const __half* __restrict__ x8, const float* __restrict__ dinv,
                            float* __restrict__ agg){
    __shared__ float ost[192];
    int tid = threadIdx.x;
    int wv = tid >> 6, l = tid & 63, g = l >> 3, q = l & 7;
    int node = (blockIdx.x << 5) + (wv << 3) + g;
    unsigned pk = (unsigned)rp[node];
    int s0 = (int)(pk & 0xFFFFFu);
    int deg = (int)(pk >> 20);
    float acc[6] = {0.f,0.f,0.f,0.f,0.f,0.f};
    if (q == 0) {   // self row (already dinv-scaled)
        H8 r; r.f4 = *(const float4*)&x8[(size_t)node * 8];
        #pragma unroll
        for (int i = 0; i < 3; i++) {
            float2 f = __half22float2(r.h2[i]);
            acc[2*i] = f.x; acc[2*i+1] = f.y;
        }
    }
    for (int base = 0; base < deg; base += 8) {
        int s = base + q;
        int c = col[s0 + s];
        int u = (s < deg) ? c : node;
        float wvv = (s < deg) ? 1.f : 0.f;
        H8 r; r.f4 = *(const float4*)&x8[(size_t)u * 8];
        #pragma unroll
        for (int i = 0; i < 3; i++) {
            float2 f = __half22float2(r.h2[i]);
            acc[2*i] += wvv * f.x; acc[2*i+1] += wvv * f.y;
        }
    }
    #pragma unroll
    for (int m = 1; m < 8; m <<= 1) {
        #pragma unroll
        for (int i = 0; i < 6; i++) acc[i] += __shfl_xor(acc[i], m, 8);
    }
    if (q == 0) {
        float dd = dinv[node];
        int slot = (wv << 3) + g;
        #pragma unroll
        for (int i = 0; i < 6; i++) ost[slot * 6 + i] = dd * acc[i];
    }
    __syncthreads();
    if (tid < 48)
        *(float4*)&agg[(size_t)blockIdx.x * 192 + (tid << 2)] = *(float4*)&ost[tid << 2];
}

// ---------------- prot L1 GAT gather: 16 slots x 4 lanes, inline exp weights ----------------
__global__ void k_gather_x32(const int* __restrict__ rp, const int* __restrict__ col,
                             const __half* __restrict__ x32, const float* __restrict__ es,
                             const float* __restrict__ ed_, float* __restrict__ agg){
    int tid = threadIdx.x;
    int node = (blockIdx.x << 2) + (tid >> 6);
    int l = tid & 63, g = l >> 2, q = l & 3;
    unsigned pk = (unsigned)rp[node];
    int s0 = (int)(pk & 0x1FFFFFu);
    int deg = (int)(pk >> 21);
    float edv = ed_[node];
    float selfw = __expf(leaky(es[node] + edv));
    float acc[8] = {0.f,0.f,0.f,0.f,0.f,0.f,0.f,0.f};
    float den = (l == 0) ? selfw : 0.f;
    if (g == 0 && q < 3) {
        H8 r; r.f4 = *(const float4*)&x32[(size_t)node * 32 + (q << 3)];
        #pragma unroll
        for (int i = 0; i < 4; i++) {
            float2 f = __half22float2(r.h2[i]);
            acc[2*i] = selfw * f.x; acc[2*i+1] = selfw * f.y;
        }
    }
    for (int base = 0; base < deg; base += 16) {
        int s = base + g;
        int c = col[s0 + s];
        int u = (s < deg) ? c : node;
        float wvv = (s < deg) ? __expf(leaky(es[u] + edv)) : 0.f;
        if (q < 3) {
            H8 r; r.f4 = *(const float4*)&x32[(size_t)u * 32 + (q << 3)];
            #pragma unroll
            for (int i = 0; i < 4; i++) {
                float2 f = __half22float2(r.h2[i]);
                acc[2*i] += wvv * f.x; acc[2*i+1] += wvv * f.y;
            }
        }
        if (q == 0) den += wvv;
    }
    #pragma unroll
    for (int m = 4; m <= 32; m <<= 1) {
        #pragma unroll
        for (int i = 0; i < 8; i++) acc[i] += __shfl_xor(acc[i], m, 64);
        den += __shfl_xor(den, m, 64);
    }
    den = __shfl(den, 0, 64);
    float inv = 1.f / den;
    if (g == 0) {
        if (q < 2) {
            float4 v0 = make_float4(acc[0]*inv, acc[1]*inv, acc[2]*inv, acc[3]*inv);
            float4 v1 = make_float4(acc[4]*inv, acc[5]*inv, acc[6]*inv, acc[7]*inv);
            *(float4*)&agg[(size_t)node * 20 + (q << 3)]     = v0;
            *(float4*)&agg[(size_t)node * 20 + (q << 3) + 4] = v1;
        } else if (q == 2) {
            float4 v0 = make_float4(acc[0]*inv, acc[1]*inv, acc[2]*inv, acc[3]*inv);
            *(float4*)&agg[(size_t)node * 20 + 16] = v0;
        }
    }
}

// ---------------- fused MLP: agg @ W1 + b1 -> relu -> @ W2 -> fp16 (+att dots / dinv scale) ----------------
template<int D, int ATT, int SCALE>
__global__ void k_mlp(const float* __restrict__ agg, const float* __restrict__ W1,
                      const float* __restrict__ b1, const float* __restrict__ W2,
                      const float* __restrict__ as_, const float* __restrict__ ad_,
                      __half* __restrict__ hout, float* __restrict__ es,
                      float* __restrict__ ed_, const float* __restrict__ dinv){
    __shared__ float W1s[D * 64];
    __shared__ float W2s[64 * 64];
    __shared__ float A[16][D + 1];
    __shared__ float X1[16][68];
    int tid = threadIdx.x;
    for (int k = tid; k < D * 64; k += 256) W1s[k] = W1[k];
    for (int k = tid * 4; k < 4096; k += 1024)
        *(float4*)&W2s[k] = *(const float4*)&W2[k];
    int nd = tid >> 4, q = tid & 15;
    size_t node = (size_t)blockIdx.x * 16 + nd;
    for (int k = q; k < D; k += 16) A[nd][k] = agg[node * D + k];
    __syncthreads();
    float4 h1 = *(const float4*)&b1[q << 2];
    #pragma unroll
    for (int k = 0; k < D; k++) {
        float xk = A[nd][k];
        float4 w4 = *(const float4*)&W1s[(k << 6) + (q << 2)];
        h1.x += xk * w4.x; h1.y += xk * w4.y; h1.z += xk * w4.z; h1.w += xk * w4.w;
    }
    h1.x = fmaxf(h1.x, 0.f); h1.y = fmaxf(h1.y, 0.f);
    h1.z = fmaxf(h1.z, 0.f); h1.w = fmaxf(h1.w, 0.f);
    *(float4*)&X1[nd][q << 2] = h1;
    __syncthreads();
    float4 acc = {0.f, 0.f, 0.f, 0.f};
    #pragma unroll 8
    for (int k = 0; k < 64; k++) {
        float xk = X1[nd][k];
        float4 w4 = *(const float4*)&W2s[(k << 6) + (q << 2)];
        acc.x += xk * w4.x; acc.y += xk * w4.y; acc.z += xk * w4.z; acc.w += xk * w4.w;
    }
    float4 st = acc;
    if (SCALE) {
        float dd = dinv[node];
        st.x *= dd; st.y *= dd; st.z *= dd; st.w *= dd;
    }
    union { __half2 h2[2]; float2 f2; } u;
    u.h2[0] = __floats2half2_rn(st.x, st.y);
    u.h2[1] = __floats2half2_rn(st.z, st.w);
    *(float2*)&hout[node * 64 + (q << 2)] = u.f2;
    if (ATT) {
        int f = q << 2;
        float xa = acc.x * as_[f] + acc.y * as_[f + 1] + acc.z * as_[f + 2] + acc.w * as_[f + 3];
        float ya = acc.x * ad_[f] + acc.y * ad_[f + 1] + acc.z * ad_[f + 2] + acc.w * ad_[f + 3];
        #pragma unroll
        for (int m = 1; m < 16; m <<= 1) {
            xa += __shfl_xor(xa, m, 16);
            ya += __shfl_xor(ya, m, 16);
        }
        if (q == 0) { es[node] = xa; ed_[node] = ya; }
    }
}

// ---------------- mol layer-2 gather: 8 slots x 8 lanes, pre-scaled rows ----------------
__global__ void k_gather64h_gcn(const int* __restrict__ rp, const int* __restrict__ col,
                                const __half* __restrict__ hh, const float* __restrict__ dinv,
                                const float* __restrict__ b, float* __restrict__ out){
    int tid = threadIdx.x;
    int node = (blockIdx.x << 2) + (tid >> 6);
    int l = tid & 63, g = l >> 3, q = l & 7;
    unsigned pk = (unsigned)rp[node];
    int s0 = (int)(pk & 0xFFFFFu);
    int deg = (int)(pk >> 20);
    float acc[8] = {0.f,0.f,0.f,0.f,0.f,0.f,0.f,0.f};
    if (g == 0) {   // self row (pre-scaled by dinv[node])
        H8 r; r.f4 = *(const float4*)&hh[(size_t)node * 64 + (q << 3)];
        #pragma unroll
        for (int i = 0; i < 4; i++) {
            float2 f = __half22float2(r.h2[i]);
            acc[2*i]     = f.x;
            acc[2*i + 1] = f.y;
        }
    }
    for (int base = 0; base < deg; base += 8) {
        int s = base + g;
        int c = col[s0 + s];
        int u = (s < deg) ? c : node;
        float wvv = (s < deg) ? 1.f : 0.f;
        H8 r; r.f4 = *(const float4*)&hh[(size_t)u * 64 + (q << 3)];
        #pragma unroll
        for (int i = 0; i < 4; i++) {
            float2 f = __half22float2(r.h2[i]);
            acc[2*i]     += wvv * f.x;
            acc[2*i + 1] += wvv * f.y;
        }
    }
    #pragma unroll
    for (int m = 8; m <= 32; m <<= 1) {
        #pragma unroll
        for (int i = 0; i < 8; i++) acc[i] += __shfl_xor(acc[i], m, 64);
    }
    if (g == 0) {
        float sc = dinv[node];
        int f = q << 3;
        float4 v0, v1;
        v0.x = acc[0]*sc + b[f];     v0.y = acc[1]*sc + b[f+1];
        v0.z = acc[2]*sc + b[f+2];   v0.w = acc[3]*sc + b[f+3];
        v1.x = acc[4]*sc + b[f+4];   v1.y = acc[5]*sc + b[f+5];
        v1.z = acc[6]*sc + b[f+6];   v1.w = acc[7]*sc + b[f+7];
        *(float4*)&out[(size_t)node * 64 + f]     = v0;
        *(float4*)&out[(size_t)node * 64 + f + 4] = v1;
    }
}

// ---------------- prot layer-2 gather: 8 groups x 8 lanes, 2 slots/group/iter ----------------
// 16 rows in flight with single 16-B loads per lane; acc[8]; inline exp weights.
__global__ void k_gather64h_gat(const int* __restrict__ rp, const int* __restrict__ col,
                                const __half* __restrict__ hh, const float* __restrict__ es,
                                const float* __restrict__ ed_, const float* __restrict__ b,
                                float* __restrict__ out){
    int tid = threadIdx.x;
    int node = (blockIdx.x << 2) + (tid >> 6);
    int l = tid & 63, g = l >> 3, q = l & 7;
    unsigned pk = (unsigned)rp[node];
    int s0 = (int)(pk & 0x1FFFFFu);
    int deg = (int)(pk >> 21);
    float edv = ed_[node];
    float selfw = __expf(leaky(es[node] + edv));
    float acc[8] = {0.f,0.f,0.f,0.f,0.f,0.f,0.f,0.f};
    float den = (l == 0) ? selfw : 0.f;
    if (g == 0) {
        H8 r; r.f4 = *(const float4*)&hh[(size_t)node * 64 + (q << 3)];
        #pragma unroll
        for (int i = 0; i < 4; i++) {
            float2 f = __half22float2(r.h2[i]);
            acc[2*i]     = selfw * f.x;
            acc[2*i + 1] = selfw * f.y;
        }
    }
    for (int base = 0; base < deg; base += 16) {
        int sA = base + g, sB = base + g + 8;
        int cA = col[s0 + sA], cB = col[s0 + sB];   // +64 slack allocated
        int uA = (sA < deg) ? cA : node;
        int uB = (sB < deg) ? cB : node;
        float eA = es[uA], eB = es[uB];
        float wA = (sA < deg) ? __expf(leaky(eA + edv)) : 0.f;
        float wB = (sB < deg) ? __expf(leaky(eB + edv)) : 0.f;
        H8 rA, rB;
        rA.f4 = *(const float4*)&hh[(size_t)uA * 64 + (q << 3)];
        rB.f4 = *(const float4*)&hh[(size_t)uB * 64 + (q << 3)];
        #pragma unroll
        for (int i = 0; i < 4; i++) {
            float2 fA = __half22float2(rA.h2[i]);
            float2 fB = __half22float2(rB.h2[i]);
            acc[2*i]     += wA * fA.x + wB * fB.x;
            acc[2*i + 1] += wA * fA.y + wB * fB.y;
        }
        if (q == 0) den += wA + wB;
    }
    #pragma unroll
    for (int m = 8; m <= 32; m <<= 1) {
        #pragma unroll
        for (int i = 0; i < 8; i++) acc[i] += __shfl_xor(acc[i], m, 64);
        den += __shfl_xor(den, m, 64);
    }
    den = __shfl(den, 0, 64);
    if (g == 0) {
        float sc = 1.f / den;
        int f = q << 3;
        float4 v0, v1;
        v0.x = acc[0]*sc + b[f];     v0.y = acc[1]*sc + b[f+1];
        v0.z = acc[2]*sc + b[f+2];   v0.w = acc[3]*sc + b[f+3];
        v1.x = acc[4]*sc + b[f+4];   v1.y = acc[5]*sc + b[f+5];
        v1.z = acc[6]*sc + b[f+6];   v1.w = acc[7]*sc + b[f+7];
        *(float4*)&out[(size_t)node * 64 + f]     = v0;
        *(float4*)&out[(size_t)node * 64 + f + 4] = v1;
    }
}

// ---------------- mol pooling ----------------
__global__ void k_segpool(const int* __restrict__ gstart, const int* __restrict__ gend,
                          const float* __restrict__ x, float* __restrict__ gsum){
    int gph = blockIdx.x, t = threadIdx.x;
    int rg = t >> 4, q = t & 15;
    int s = gstart[gph], c = gend[gph] - gstart[gph];
    float4 a = {0.f, 0.f, 0.f, 0.f};
    for (int i = rg; i < c; i += 4) {
        float4 v = *(const float4*)&x[(size_t)(s + i) * 64 + (q << 2)];
        a.x += v.x; a.y += v.y; a.z += v.z; a.w += v.w;
    }
    #pragma unroll
    for (int m = 16; m <= 32; m <<= 1) {
        a.x += __shfl_xor(a.x, m, 64);
        a.y += __shfl_xor(a.y, m, 64);
        a.z += __shfl_xor(a.z, m, 64);
        a.w += __shfl_xor(a.w, m, 64);
    }
    if (rg == 0) *(float4*)&gsum[gph * 64 + (q << 2)] = a;
}

// ---------------- prot pooling ----------------
__global__ void k_pool_prot(const float* __restrict__ x, float* __restrict__ psum, int n){
    __shared__ float red[4][64];
    int t = threadIdx.x, lane = t & 63, wv = t >> 6;
    const float4* x4 = (const float4*)x;
    int total = n * 16;
    float4 a = {0.f, 0.f, 0.f, 0.f};
    for (int i = blockIdx.x * 256 + t; i < total; i += gridDim.x * 256) {
        float4 v = x4[i];
        a.x += v.x; a.y += v.y; a.z += v.z; a.w += v.w;
    }
    #pragma unroll
    for (int m = 16; m <= 32; m <<= 1) {
        a.x += __shfl_xor(a.x, m, 64);
        a.y += __shfl_xor(a.y, m, 64);
        a.z += __shfl_xor(a.z, m, 64);
        a.w += __shfl_xor(a.w, m, 64);
    }
    if (lane < 16) *(float4*)&red[wv][lane << 2] = a;
    __syncthreads();
    if (t < 64) {
        float s = red[0][t] + red[1][t] + red[2][t] + red[3][t];
        atomicAdd(&psum[t], s);
    }
}

// ---------------- fused classifier ----------------
__global__ void k_cls(const float* __restrict__ gsum, const int* __restrict__ gstart,
                      const int* __restrict__ gend, const float* __restrict__ psum,
                      const float* __restrict__ W1, const float* __restrict__ b1,
                      const float* __restrict__ w2, const float* __restrict__ b2,
                      float* __restrict__ out){
    __shared__ float W1s[128 * 64];
    int tid = threadIdx.x;
    for (int k = tid; k < 128 * 64; k += 256) W1s[k] = W1[k];
    __syncthreads();
    int g = blockIdx.x * 4 + (tid >> 6);
    int j = tid & 63;
    float cntf = (float)(gend[g] - gstart[g]);
    float inv = 1.0f / fmaxf(cntf, 1.0f);
    const float invp = 1.0f / (float)NP;
    float acc = b1[j];
    #pragma unroll 8
    for (int k = 0; k < 64; k++) acc += (gsum[g * 64 + k] * inv) * W1s[k * 64 + j];
    #pragma unroll 8
    for (int k = 0; k < 64; k++) acc += (psum[k] * invp) * W1s[(64 + k) * 64 + j];
    float v = fmaxf(acc, 0.f) * w2[j];
    #pragma unroll
    for (int off = 32; off > 0; off >>= 1) v += __shfl_down(v, off, 64);
    if (j == 0) out[g] = 1.0f / (1.0f + expf(-(v + b2[0])));
}

extern "C" void kernel_launch(void* const* d_in, const int* in_sizes, int n_in,
                              void* d_out, int out_size, void* d_ws, size_t ws_size,
                              hipStream_t stream) {
    const float* mol_x   = (const float*)d_in[0];
    const int*   mol_ei  = (const int*)d_in[1];
    const int*   mol_bat = (const int*)d_in[2];
    const float* prot_x  = (const float*)d_in[3];
    const int*   prot_ei = (const int*)d_in[4];
    const float* gcn_w1  = (const float*)d_in[5];
    const float* gcn_b1  = (const float*)d_in[6];
    const float* gcn_w2  = (const float*)d_in[7];
    const float* gcn_b2  = (const float*)d_in[8];
    const float* gat_w1  = (const float*)d_in[9];
    const float* gat_as1 = (const float*)d_in[10];
    const float* gat_ad1 = (const float*)d_in[11];
    const float* gat_b1  = (const float*)d_in[12];
    const float* gat_w2  = (const float*)d_in[13];
    const float* gat_as2 = (const float*)d_in[14];
    const float* gat_ad2 = (const float*)d_in[15];
    const float* gat_b2  = (const float*)d_in[16];
    const float* cls_w1  = (const float*)d_in[17];
    const float* cls_b1  = (const float*)d_in[18];
    const float* cls_w2  = (const float*)d_in[19];
    const float* cls_b2  = (const float*)d_in[20];
    float* out = (float*)d_out;

    float* ws_f = (float*)d_ws;

    // ---- persistent tail; [gstart .. coarseP+512) is one contiguous zeroed region ----
    float* T       = ws_f + 16777216;
    float* gsum    = T;                       // 262,144 floats (no init needed)
    int*   gstart  = (int*)(T + 262144);      // 4,096 ints (zeroed)
    int*   gend    = (int*)(T + 266240);      // 4,096 ints (zeroed)
    float* psum    = T + 270336;              // 64 floats (zeroed)
    int*   coarseM = (int*)(T + 270400);      // 512 ints (zeroed)
    int*   coarseP = (int*)(T + 270912);      // 512 ints (zeroed)
    int*   cstartM = (int*)(T + 271424);      // 513
    int*   cursorM = (int*)(T + 271937);      // 512
    int*   cstartP = (int*)(T + 272449);      // 513
    int*   cursorP = (int*)(T + 272962);      // 512

    // ---- mol-phase layout ----
    float*    molout = ws_f;                             // [0, 8388608)
    unsigned* bufM   = (unsigned*)ws_f;                  // EM (dead before molout)
    __half*   h2hM   = (__half*)(ws_f + 8388608);        // [8388608, 12582912)
    int*      molCOL = (int*)(ws_f + 12582912);          // EM+64
    int*      molRP  = (int*)(ws_f + 13107264);          // NM
    float*    dinvM  = ws_f + 13238352;                  // NM
    __half*   x8h    = (__half*)(ws_f + 13369440);       // NM*8 halves
    float*    aggM   = ws_f + 13893792;                  // NM*6

    // ---- prot-phase layout (mol fully done first) ----
    float*    protout = ws_f;                            // [0, 6400000)
    unsigned* bufP    = (unsigned*)ws_f;                 // EP (dead before protout)
    __half*   h2hP    = (__half*)(ws_f + 6400000);       // [6400000, 9600000)
    int*      protCOL = (int*)(ws_f + 9600000);          // EP+64
    int*      protRP  = (int*)(ws_f + 11200064);         // NP
    float*    es      = ws_f + 11300080;                 // NP
    float*    ed_     = ws_f + 11400080;                 // NP
    __half*   x32h    = (__half*)(ws_f + 11500080);      // NP*32 halves
    float*    aggP    = ws_f + 13100144;                 // NP*20

    const int KM = 512;   // NM/256
    const int KPb = 391;  // cdiv(NP,256)

    // single upfront zero of gstart+gend+psum+coarseM+coarseP (contiguous)
    (void)hipMemsetAsync(gstart, 0, (size_t)(4096 + 4096 + 64 + 512 + 512) * sizeof(int), stream);

    // ================= mol branch =================
    k_coarse_hist<2048><<<cdiv(EM,2048),256,0,stream>>>(mol_ei + EM, coarseM, EM, KM);
    k_coarse_scan<<<1,512,0,stream>>>(coarseM, cstartM, cursorM, KM, EM);
    k_part<2048,8><<<cdiv(EM,2048),256,0,stream>>>(mol_ei, cursorM, bufM, EM, KM);
    k_fine<20,1><<<KM,256,0,stream>>>(bufM, cstartM, molRP, molCOL, dinvM, NM, KM);
    k_molprep<<<2*cdiv(NM,256),256,0,stream>>>(mol_x, dinvM, x8h, mol_bat, gstart, gend, NM, cdiv(NM,256));
    k_gather_x8<<<NM/32,256,0,stream>>>(molRP, molCOL, x8h, dinvM, aggM);
    k_mlp<6,0,1><<<NM/16,256,0,stream>>>(aggM, gcn_w1, gcn_b1, gcn_w2, nullptr, nullptr, h2hM, nullptr, nullptr, dinvM);
    k_gather64h_gcn<<<NM/4,256,0,stream>>>(molRP, molCOL, h2hM, dinvM, gcn_b2, molout);
    k_segpool<<<NG,64,0,stream>>>(gstart, gend, molout, gsum);

    // ================= prot branch =================
    k_coarse_hist<4096><<<cdiv(EP,4096),256,0,stream>>>(prot_ei + EP, coarseP, EP, KPb);
    k_coarse_scan<<<1,512,0,stream>>>(coarseP, cstartP, cursorP, KPb, EP);
    k_part<4096,16><<<cdiv(EP,4096),256,0,stream>>>(prot_ei, cursorP, bufP, EP, KPb);
    k_fine<21,0><<<KPb,256,0,stream>>>(bufP, cstartP, protRP, protCOL, nullptr, NP, KPb);
    k_prep_prot<<<cdiv(NP,256),256,0,stream>>>(prot_x, gat_w1, gat_as1, gat_ad1, x32h, es, ed_, NP);
    k_gather_x32<<<NP/4,256,0,stream>>>(protRP, protCOL, x32h, es, ed_, aggP);
    k_mlp<20,1,0><<<NP/16,256,0,stream>>>(aggP, gat_w1, gat_b1, gat_w2, gat_as2, gat_ad2, h2hP, es, ed_, nullptr);
    k_gather64h_gat<<<NP/4,256,0,stream>>>(protRP, protCOL, h2hP, es, ed_, gat_b2, protout);
    k_pool_prot<<<1024,256,0,stream>>>(protout, psum, NP);

    // ================= classifier =================
    k_cls<<<NG/4,256,0,stream>>>(gsum, gstart, gend, psum, cls_w1, cls_b1, cls_w2, cls_b2, out);
}

// Round 16
// 425.234 us; speedup vs baseline: 1.2271x; 1.0522x over previous
//
#include <hip/hip_runtime.h>
#include <hip/hip_fp16.h>

#define NM 131072   // mol nodes
#define EM 524288   // mol edges
#define NG 4096     // graphs
#define DM 6        // mol in dim
#define NP 100000   // prot nodes
#define EP 1600000  // prot edges
#define DP 20       // prot in dim

static inline int cdiv(int a, int b){ return (a + b - 1) / b; }

__device__ __forceinline__ float leaky(float x){ return x > 0.f ? x : 0.2f * x; }

union H8 { float4 f4; __half2 h2[4]; };

// ================= merged bucketed CSR build (mol + prot in one launch) =================
// mol: 256 blocks, CHUNK 2048 ; prot: 391 blocks, CHUNK 4096
__global__ void k_hist2(const int* __restrict__ dstM, const int* __restrict__ dstP,
                        int* __restrict__ coarseM, int* __restrict__ coarseP){
    __shared__ int lh[512];
    int t = threadIdx.x;
    const int* dst; int* coarse; int K, E, base, chunk;
    if (blockIdx.x < 256) { dst = dstM; coarse = coarseM; K = 512; E = EM; chunk = 2048; base = blockIdx.x * 2048; }
    else                  { dst = dstP; coarse = coarseP; K = 391; E = EP; chunk = 4096; base = (blockIdx.x - 256) * 4096; }
    for (int i = t; i < K; i += 256) lh[i] = 0;
    __syncthreads();
    int end = min(base + chunk, E);
    for (int e = base + t; e < end; e += 256)
        atomicAdd(&lh[dst[e] >> 8], 1);
    __syncthreads();
    for (int i = t; i < K; i += 256)
        if (lh[i]) atomicAdd(&coarse[i], lh[i]);
}

// 2 blocks x 512: block 0 = mol scan, block 1 = prot scan
__global__ void k_scan2(const int* __restrict__ coarseM, int* __restrict__ cstartM, int* __restrict__ cursorM,
                        const int* __restrict__ coarseP, int* __restrict__ cstartP, int* __restrict__ cursorP){
    const int* coarse; int* cstart; int* cursor; int K, E;
    if (blockIdx.x == 0) { coarse = coarseM; cstart = cstartM; cursor = cursorM; K = 512; E = EM; }
    else                 { coarse = coarseP; cstart = cstartP; cursor = cursorP; K = 391; E = EP; }
    int t = threadIdx.x, lane = t & 63, wid = t >> 6;
    int v0 = (t < K) ? coarse[t] : 0;
    int v = v0;
    #pragma unroll
    for (int off = 1; off < 64; off <<= 1) {
        int x = __shfl_up(v, off, 64);
        if (lane >= off) v += x;
    }
    __shared__ int ws[8];
    if (lane == 63) ws[wid] = v;
    __syncthreads();
    int add = 0;
    for (int w = 0; w < wid; w++) add += ws[w];
    int excl = v + add - v0;
    if (t < K) { cstart[t] = excl; cursor[t] = excl; }
    if (t == K - 1) cstart[K] = excl + v0;
}

// mol: 128 blocks, prot: 391 blocks; CHUNK 4096, EPT 16 for both
__global__ void k_part2(const int* __restrict__ eiM, int* __restrict__ cursorM, unsigned* __restrict__ bufM,
                        const int* __restrict__ eiP, int* __restrict__ cursorP, unsigned* __restrict__ bufP){
    __shared__ int lh[512];
    __shared__ int lbase[512];
    const int* ei; int* cursor; unsigned* buf; int E, K, base;
    if (blockIdx.x < 128) { ei = eiM; cursor = cursorM; buf = bufM; E = EM; K = 512; base = blockIdx.x * 4096; }
    else                  { ei = eiP; cursor = cursorP; buf = bufP; E = EP; K = 391; base = (blockIdx.x - 128) * 4096; }
    int t = threadIdx.x;
    for (int i = t; i < K; i += 256) lh[i] = 0;
    __syncthreads();
    int end = min(base + 4096, E);
    unsigned pay[16]; int bslot[16];
    int cnt = 0;
    for (int e = base + t; e < end; e += 256) {
        int u = ei[e], v = ei[E + e];
        int b = v >> 8;
        int ls = atomicAdd(&lh[b], 1);
        pay[cnt] = ((unsigned)(v & 255) << 24) | (unsigned)u;
        bslot[cnt] = (b << 13) | ls;
        cnt++;
    }
    __syncthreads();
    for (int i = t; i < K; i += 256)
        lbase[i] = lh[i] ? atomicAdd(&cursor[i], lh[i]) : 0;
    __syncthreads();
    for (int j = 0; j < cnt; j++) {
        int b = bslot[j] >> 13, ls = bslot[j] & 8191;
        buf[lbase[b] + ls] = pay[j];
    }
}

// mol: blocks [0,512) OBITS 20 + dinv ; prot: blocks [512,903) OBITS 21
__global__ void k_fine2(const unsigned* __restrict__ bufM, const int* __restrict__ cstartM,
                        int* __restrict__ molRP, int* __restrict__ molCOL, float* __restrict__ dinv,
                        const unsigned* __restrict__ bufP, const int* __restrict__ cstartP,
                        int* __restrict__ protRP, int* __restrict__ protCOL){
    int t = threadIdx.x;
    int k; const unsigned* buf; const int* cstart; int* rp; int* col; int n, OB, dv;
    if (blockIdx.x < 512) { k = blockIdx.x;       buf = bufM; cstart = cstartM; rp = molRP;  col = molCOL;  n = NM; OB = 20; dv = 1; }
    else                  { k = blockIdx.x - 512; buf = bufP; cstart = cstartP; rp = protRP; col = protCOL; n = NP; OB = 21; dv = 0; }
    int start = cstart[k], end = cstart[k + 1];
    __shared__ int cnt[256];
    __shared__ int cur[256];
    cnt[t] = 0;
    __syncthreads();
    for (int p = start + t; p < end; p += 256)
        atomicAdd(&cnt[buf[p] >> 24], 1);
    __syncthreads();
    int v0 = cnt[t];
    int lane = t & 63, wid = t >> 6;
    int v = v0;
    #pragma unroll
    for (int off = 1; off < 64; off <<= 1) {
        int x = __shfl_up(v, off, 64);
        if (lane >= off) v += x;
    }
    __shared__ int ws[4];
    if (lane == 63) ws[wid] = v;
    __syncthreads();
    int add = 0;
    for (int w = 0; w < wid; w++) add += ws[w];
    int excl = v + add - v0;
    int ofs = start + excl;
    cur[t] = ofs;
    int idx = (k << 8) + t;
    if (idx < n) {
        rp[idx] = (int)((unsigned)ofs | ((unsigned)v0 << OB));
        if (dv) dinv[idx] = rsqrtf((float)(v0 + 1));
    }
    __syncthreads();
    for (int p = start + t; p < end; p += 256) {
        unsigned pk = buf[p];
        int slot = atomicAdd(&cur[pk >> 24], 1);
        col[slot] = (int)(pk & 0xFFFFFFu);
    }
}

// ---------------- fused: mol x -> dinv-prescaled 8-half rows + segment bounds ----------------
__global__ void k_molprep(const float* __restrict__ x, const float* __restrict__ dinv,
                          __half* __restrict__ x8, const int* __restrict__ batch,
                          int* __restrict__ gstart, int* __restrict__ gend, int n, int nbA){
    int b = blockIdx.x;
    if (b < nbA) {
        int i = b * 256 + threadIdx.x;
        if (i >= n) return;
        float dd = dinv[i];
        H8 r;
        #pragma unroll
        for (int k = 0; k < 3; k++)
            r.h2[k] = __floats2half2_rn(dd * x[i*6 + 2*k], dd * x[i*6 + 2*k + 1]);
        r.h2[3] = __floats2half2_rn(0.f, 0.f);
        *(float4*)&x8[(size_t)i * 8] = r.f4;
    } else {
        int i = (b - nbA) * 256 + threadIdx.x;
        if (i >= n) return;
        int g = batch[i];
        if (i == 0 || batch[i - 1] != g) gstart[g] = i;
        if (i == n - 1 || batch[i + 1] != g) gend[g] = i + 1;
    }
}

// ---------------- prep: prot x -> padded 32-half rows + es/ed dots ----------------
__global__ void k_prep_prot(const float* __restrict__ x, const float* __restrict__ W1,
                            const float* __restrict__ as_, const float* __restrict__ ad_,
                            __half* __restrict__ x32, float* __restrict__ es,
                            float* __restrict__ ed_, int n){
    __shared__ float vas[20], vds[20];
    int t = threadIdx.x;
    if (t < 20) {
        float s = 0.f;
        for (int j = 0; j < 64; j++) s += W1[t * 64 + j] * as_[j];
        vas[t] = s;
    } else if (t >= 32 && t < 52) {
        int k = t - 32;
        float s = 0.f;
        for (int j = 0; j < 64; j++) s += W1[k * 64 + j] * ad_[j];
        vds[k] = s;
    }
    __syncthreads();
    int i = blockIdx.x * 256 + t;
    if (i >= n) return;
    float xv[20];
    float s = 0.f, d = 0.f;
    #pragma unroll
    for (int k = 0; k < 20; k++) {
        xv[k] = x[i*20 + k];
        s += xv[k] * vas[k]; d += xv[k] * vds[k];
    }
    es[i] = s; ed_[i] = d;
    H8 r0, r1, r2, rz;
    #pragma unroll
    for (int k = 0; k < 4; k++) r0.h2[k] = __floats2half2_rn(xv[2*k],   xv[2*k+1]);
    #pragma unroll
    for (int k = 0; k < 4; k++) r1.h2[k] = __floats2half2_rn(xv[8+2*k], xv[9+2*k]);
    r2.h2[0] = __floats2half2_rn(xv[16], xv[17]);
    r2.h2[1] = __floats2half2_rn(xv[18], xv[19]);
    r2.h2[2] = __floats2half2_rn(0.f, 0.f);
    r2.h2[3] = __floats2half2_rn(0.f, 0.f);
    rz.h2[0] = rz.h2[1] = rz.h2[2] = rz.h2[3] = __floats2half2_rn(0.f, 0.f);
    *(float4*)&x32[(size_t)i * 32]      = r0.f4;
    *(float4*)&x32[(size_t)i * 32 + 8]  = r1.f4;
    *(float4*)&x32[(size_t)i * 32 + 16] = r2.f4;
    *(float4*)&x32[(size_t)i * 32 + 24] = rz.f4;
}

// ---------------- mol L1 gather: 8 lanes/node, 8 nodes/wave, pre-scaled rows ----------------
__global__ void k_gather_x8(const int* __restrict__ rp, const int* __restrict__ col,
                            const __half* __restrict__ x8, const float* __restrict__ dinv,
                            float* __restrict__ agg){
    __shared__ float ost[192];
    int tid = threadIdx.x;
    int wv = tid >> 6, l = tid & 63, g = l >> 3, q = l & 7;
    int node = (blockIdx.x << 5) + (wv << 3) + g;
    unsigned pk = (unsigned)rp[node];
    int s0 = (int)(pk & 0xFFFFFu);
    int deg = (int)(pk >> 20);
    float acc[6] = {0.f,0.f,0.f,0.f,0.f,0.f};
    if (q == 0) {
        H8 r; r.f4 = *(const float4*)&x8[(size_t)node * 8];
        #pragma unroll
        for (int i = 0; i < 3; i++) {
            float2 f = __half22float2(r.h2[i]);
            acc[2*i] = f.x; acc[2*i+1] = f.y;
        }
    }
    for (int base = 0; base < deg; base += 8) {
        int s = base + q;
        int c = col[s0 + s];
        int u = (s < deg) ? c : node;
        float wvv = (s < deg) ? 1.f : 0.f;
        H8 r; r.f4 = *(const float4*)&x8[(size_t)u * 8];
        #pragma unroll
        for (int i = 0; i < 3; i++) {
            float2 f = __half22float2(r.h2[i]);
            acc[2*i] += wvv * f.x; acc[2*i+1] += wvv * f.y;
        }
    }
    #pragma unroll
    for (int m = 1; m < 8; m <<= 1) {
        #pragma unroll
        for (int i = 0; i < 6; i++) acc[i] += __shfl_xor(acc[i], m, 8);
    }
    if (q == 0) {
        float dd = dinv[node];
        int slot = (wv << 3) + g;
        #pragma unroll
        for (int i = 0; i < 6; i++) ost[slot * 6 + i] = dd * acc[i];
    }
    __syncthreads();
    if (tid < 48)
        *(float4*)&agg[(size_t)blockIdx.x * 192 + (tid << 2)] = *(float4*)&ost[tid << 2];
}

// ---------------- prot L1 GAT gather: 16 slots x 4 lanes, inline exp weights ----------------
__global__ void k_gather_x32(const int* __restrict__ rp, const int* __restrict__ col,
                             const __half* __restrict__ x32, const float* __restrict__ es,
                             const float* __restrict__ ed_, float* __restrict__ agg){
    int tid = threadIdx.x;
    int node = (blockIdx.x << 2) + (tid >> 6);
    int l = tid & 63, g = l >> 2, q = l & 3;
    unsigned pk = (unsigned)rp[node];
    int s0 = (int)(pk & 0x1FFFFFu);
    int deg = (int)(pk >> 21);
    float edv = ed_[node];
    float selfw = __expf(leaky(es[node] + edv));
    float acc[8] = {0.f,0.f,0.f,0.f,0.f,0.f,0.f,0.f};
    float den = (l == 0) ? selfw : 0.f;
    if (g == 0 && q < 3) {
        H8 r; r.f4 = *(const float4*)&x32[(size_t)node * 32 + (q << 3)];
        #pragma unroll
        for (int i = 0; i < 4; i++) {
            float2 f = __half22float2(r.h2[i]);
            acc[2*i] = selfw * f.x; acc[2*i+1] = selfw * f.y;
        }
    }
    for (int base = 0; base < deg; base += 16) {
        int s = base + g;
        int c = col[s0 + s];
        int u = (s < deg) ? c : node;
        float wvv = (s < deg) ? __expf(leaky(es[u] + edv)) : 0.f;
        if (q < 3) {
            H8 r; r.f4 = *(const float4*)&x32[(size_t)u * 32 + (q << 3)];
            #pragma unroll
            for (int i = 0; i < 4; i++) {
                float2 f = __half22float2(r.h2[i]);
                acc[2*i] += wvv * f.x; acc[2*i+1] += wvv * f.y;
            }
        }
        if (q == 0) den += wvv;
    }
    #pragma unroll
    for (int m = 4; m <= 32; m <<= 1) {
        #pragma unroll
        for (int i = 0; i < 8; i++) acc[i] += __shfl_xor(acc[i], m, 64);
        den += __shfl_xor(den, m, 64);
    }
    den = __shfl(den, 0, 64);
    float inv = 1.f / den;
    if (g == 0) {
        if (q < 2) {
            float4 v0 = make_float4(acc[0]*inv, acc[1]*inv, acc[2]*inv, acc[3]*inv);
            float4 v1 = make_float4(acc[4]*inv, acc[5]*inv, acc[6]*inv, acc[7]*inv);
            *(float4*)&agg[(size_t)node * 20 + (q << 3)]     = v0;
            *(float4*)&agg[(size_t)node * 20 + (q << 3) + 4] = v1;
        } else if (q == 2) {
            float4 v0 = make_float4(acc[0]*inv, acc[1]*inv, acc[2]*inv, acc[3]*inv);
            *(float4*)&agg[(size_t)node * 20 + 16] = v0;
        }
    }
}

// ---------------- fused MLP: agg @ W1 + b1 -> relu -> @ W2 -> fp16 (+att dots / dinv scale) ----------------
template<int D, int ATT, int SCALE>
__global__ void k_mlp(const float* __restrict__ agg, const float* __restrict__ W1,
                      const float* __restrict__ b1, const float* __restrict__ W2,
                      const float* __restrict__ as_, const float* __restrict__ ad_,
                      __half* __restrict__ hout, float* __restrict__ es,
                      float* __restrict__ ed_, const float* __restrict__ dinv){
    __shared__ float W1s[D * 64];
    __shared__ float W2s[64 * 64];
    __shared__ float A[16][D + 1];
    __shared__ float X1[16][68];
    int tid = threadIdx.x;
    for (int k = tid; k < D * 64; k += 256) W1s[k] = W1[k];
    for (int k = tid * 4; k < 4096; k += 1024)
        *(float4*)&W2s[k] = *(const float4*)&W2[k];
    int nd = tid >> 4, q = tid & 15;
    size_t node = (size_t)blockIdx.x * 16 + nd;
    for (int k = q; k < D; k += 16) A[nd][k] = agg[node * D + k];
    __syncthreads();
    float4 h1 = *(const float4*)&b1[q << 2];
    #pragma unroll
    for (int k = 0; k < D; k++) {
        float xk = A[nd][k];
        float4 w4 = *(const float4*)&W1s[(k << 6) + (q << 2)];
        h1.x += xk * w4.x; h1.y += xk * w4.y; h1.z += xk * w4.z; h1.w += xk * w4.w;
    }
    h1.x = fmaxf(h1.x, 0.f); h1.y = fmaxf(h1.y, 0.f);
    h1.z = fmaxf(h1.z, 0.f); h1.w = fmaxf(h1.w, 0.f);
    *(float4*)&X1[nd][q << 2] = h1;
    __syncthreads();
    float4 acc = {0.f, 0.f, 0.f, 0.f};
    #pragma unroll 8
    for (int k = 0; k < 64; k++) {
        float xk = X1[nd][k];
        float4 w4 = *(const float4*)&W2s[(k << 6) + (q << 2)];
        acc.x += xk * w4.x; acc.y += xk * w4.y; acc.z += xk * w4.z; acc.w += xk * w4.w;
    }
    float4 st = acc;
    if (SCALE) {
        float dd = dinv[node];
        st.x *= dd; st.y *= dd; st.z *= dd; st.w *= dd;
    }
    union { __half2 h2[2]; float2 f2; } u;
    u.h2[0] = __floats2half2_rn(st.x, st.y);
    u.h2[1] = __floats2half2_rn(st.z, st.w);
    *(float2*)&hout[node * 64 + (q << 2)] = u.f2;
    if (ATT) {
        int f = q << 2;
        float xa = acc.x * as_[f] + acc.y * as_[f + 1] + acc.z * as_[f + 2] + acc.w * as_[f + 3];
        float ya = acc.x * ad_[f] + acc.y * ad_[f + 1] + acc.z * ad_[f + 2] + acc.w * ad_[f + 3];
        #pragma unroll
        for (int m = 1; m < 16; m <<= 1) {
            xa += __shfl_xor(xa, m, 16);
            ya += __shfl_xor(ya, m, 16);
        }
        if (q == 0) { es[node] = xa; ed_[node] = ya; }
    }
}

// ---------------- mol layer-2 gather: 8 slots x 8 lanes, pre-scaled rows ----------------
__global__ void k_gather64h_gcn(const int* __restrict__ rp, const int* __restrict__ col,
                                const __half* __restrict__ hh, const float* __restrict__ dinv,
                                const float* __restrict__ b, float* __restrict__ out){
    int tid = threadIdx.x;
    int node = (blockIdx.x << 2) + (tid >> 6);
    int l = tid & 63, g = l >> 3, q = l & 7;
    unsigned pk = (unsigned)rp[node];
    int s0 = (int)(pk & 0xFFFFFu);
    int deg = (int)(pk >> 20);
    float acc[8] = {0.f,0.f,0.f,0.f,0.f,0.f,0.f,0.f};
    if (g == 0) {
        H8 r; r.f4 = *(const float4*)&hh[(size_t)node * 64 + (q << 3)];
        #pragma unroll
        for (int i = 0; i < 4; i++) {
            float2 f = __half22float2(r.h2[i]);
            acc[2*i]     = f.x;
            acc[2*i + 1] = f.y;
        }
    }
    for (int base = 0; base < deg; base += 8) {
        int s = base + g;
        int c = col[s0 + s];
        int u = (s < deg) ? c : node;
        float wvv = (s < deg) ? 1.f : 0.f;
        H8 r; r.f4 = *(const float4*)&hh[(size_t)u * 64 + (q << 3)];
        #pragma unroll
        for (int i = 0; i < 4; i++) {
            float2 f = __half22float2(r.h2[i]);
            acc[2*i]     += wvv * f.x;
            acc[2*i + 1] += wvv * f.y;
        }
    }
    #pragma unroll
    for (int m = 8; m <= 32; m <<= 1) {
        #pragma unroll
        for (int i = 0; i < 8; i++) acc[i] += __shfl_xor(acc[i], m, 64);
    }
    if (g == 0) {
        float sc = dinv[node];
        int f = q << 3;
        float4 v0, v1;
        v0.x = acc[0]*sc + b[f];     v0.y = acc[1]*sc + b[f+1];
        v0.z = acc[2]*sc + b[f+2];   v0.w = acc[3]*sc + b[f+3];
        v1.x = acc[4]*sc + b[f+4];   v1.y = acc[5]*sc + b[f+5];
        v1.z = acc[6]*sc + b[f+6];   v1.w = acc[7]*sc + b[f+7];
        *(float4*)&out[(size_t)node * 64 + f]     = v0;
        *(float4*)&out[(size_t)node * 64 + f + 4] = v1;
    }
}

// ---------------- prot layer-2 gather: 8 groups x 8 lanes, 2 slots/group/iter ----------------
__global__ void k_gather64h_gat(const int* __restrict__ rp, const int* __restrict__ col,
                                const __half* __restrict__ hh, const float* __restrict__ es,
                                const float* __restrict__ ed_, const float* __restrict__ b,
                                float* __restrict__ out){
    int tid = threadIdx.x;
    int node = (blockIdx.x << 2) + (tid >> 6);
    int l = tid & 63, g = l >> 3, q = l & 7;
    unsigned pk = (unsigned)rp[node];
    int s0 = (int)(pk & 0x1FFFFFu);
    int deg = (int)(pk >> 21);
    float edv = ed_[node];
    float selfw = __expf(leaky(es[node] + edv));
    float acc[8] = {0.f,0.f,0.f,0.f,0.f,0.f,0.f,0.f};
    float den = (l == 0) ? selfw : 0.f;
    if (g == 0) {
        H8 r; r.f4 = *(const float4*)&hh[(size_t)node * 64 + (q << 3)];
        #pragma unroll
        for (int i = 0; i < 4; i++) {
            float2 f = __half22float2(r.h2[i]);
            acc[2*i]     = selfw * f.x;
            acc[2*i + 1] = selfw * f.y;
        }
    }
    for (int base = 0; base < deg; base += 16) {
        int sA = base + g, sB = base + g + 8;
        int cA = col[s0 + sA], cB = col[s0 + sB];
        int uA = (sA < deg) ? cA : node;
        int uB = (sB < deg) ? cB : node;
        float eA = es[uA], eB = es[uB];
        float wA = (sA < deg) ? __expf(leaky(eA + edv)) : 0.f;
        float wB = (sB < deg) ? __expf(leaky(eB + edv)) : 0.f;
        H8 rA, rB;
        rA.f4 = *(const float4*)&hh[(size_t)uA * 64 + (q << 3)];
        rB.f4 = *(const float4*)&hh[(size_t)uB * 64 + (q << 3)];
        #pragma unroll
        for (int i = 0; i < 4; i++) {
            float2 fA = __half22float2(rA.h2[i]);
            float2 fB = __half22float2(rB.h2[i]);
            acc[2*i]     += wA * fA.x + wB * fB.x;
            acc[2*i + 1] += wA * fA.y + wB * fB.y;
        }
        if (q == 0) den += wA + wB;
    }
    #pragma unroll
    for (int m = 8; m <= 32; m <<= 1) {
        #pragma unroll
        for (int i = 0; i < 8; i++) acc[i] += __shfl_xor(acc[i], m, 64);
        den += __shfl_xor(den, m, 64);
    }
    den = __shfl(den, 0, 64);
    if (g == 0) {
        float sc = 1.f / den;
        int f = q << 3;
        float4 v0, v1;
        v0.x = acc[0]*sc + b[f];     v0.y = acc[1]*sc + b[f+1];
        v0.z = acc[2]*sc + b[f+2];   v0.w = acc[3]*sc + b[f+3];
        v1.x = acc[4]*sc + b[f+4];   v1.y = acc[5]*sc + b[f+5];
        v1.z = acc[6]*sc + b[f+6];   v1.w = acc[7]*sc + b[f+7];
        *(float4*)&out[(size_t)node * 64 + f]     = v0;
        *(float4*)&out[(size_t)node * 64 + f + 4] = v1;
    }
}

// ---------------- mol pooling ----------------
__global__ void k_segpool(const int* __restrict__ gstart, const int* __restrict__ gend,
                          const float* __restrict__ x, float* __restrict__ gsum){
    int gph = blockIdx.x, t = threadIdx.x;
    int rg = t >> 4, q = t & 15;
    int s = gstart[gph], c = gend[gph] - gstart[gph];
    float4 a = {0.f, 0.f, 0.f, 0.f};
    for (int i = rg; i < c; i += 4) {
        float4 v = *(const float4*)&x[(size_t)(s + i) * 64 + (q << 2)];
        a.x += v.x; a.y += v.y; a.z += v.z; a.w += v.w;
    }
    #pragma unroll
    for (int m = 16; m <= 32; m <<= 1) {
        a.x += __shfl_xor(a.x, m, 64);
        a.y += __shfl_xor(a.y, m, 64);
        a.z += __shfl_xor(a.z, m, 64);
        a.w += __shfl_xor(a.w, m, 64);
    }
    if (rg == 0) *(float4*)&gsum[gph * 64 + (q << 2)] = a;
}

// ---------------- prot pooling ----------------
__global__ void k_pool_prot(const float* __restrict__ x, float* __restrict__ psum, int n){
    __shared__ float red[4][64];
    int t = threadIdx.x, lane = t & 63, wv = t >> 6;
    const float4* x4 = (const float4*)x;
    int total = n * 16;
    float4 a = {0.f, 0.f, 0.f, 0.f};
    for (int i = blockIdx.x * 256 + t; i < total; i += gridDim.x * 256) {
        float4 v = x4[i];
        a.x += v.x; a.y += v.y; a.z += v.z; a.w += v.w;
    }
    #pragma unroll
    for (int m = 16; m <= 32; m <<= 1) {
        a.x += __shfl_xor(a.x, m, 64);
        a.y += __shfl_xor(a.y, m, 64);
        a.z += __shfl_xor(a.z, m, 64);
        a.w += __shfl_xor(a.w, m, 64);
    }
    if (lane < 16) *(float4*)&red[wv][lane << 2] = a;
    __syncthreads();
    if (t < 64) {
        float s = red[0][t] + red[1][t] + red[2][t] + red[3][t];
        atomicAdd(&psum[t], s);
    }
}

// ---------------- fused classifier ----------------
__global__ void k_cls(const float* __restrict__ gsum, const int* __restrict__ gstart,
                      const int* __restrict__ gend, const float* __restrict__ psum,
                      const float* __restrict__ W1, const float* __restrict__ b1,
                      const float* __restrict__ w2, const float* __restrict__ b2,
                      float* __restrict__ out){
    __shared__ float W1s[128 * 64];
    int tid = threadIdx.x;
    for (int k = tid; k < 128 * 64; k += 256) W1s[k] = W1[k];
    __syncthreads();
    int g = blockIdx.x * 4 + (tid >> 6);
    int j = tid & 63;
    float cntf = (float)(gend[g] - gstart[g]);
    float inv = 1.0f / fmaxf(cntf, 1.0f);
    const float invp = 1.0f / (float)NP;
    float acc = b1[j];
    #pragma unroll 8
    for (int k = 0; k < 64; k++) acc += (gsum[g * 64 + k] * inv) * W1s[k * 64 + j];
    #pragma unroll 8
    for (int k = 0; k < 64; k++) acc += (psum[k] * invp) * W1s[(64 + k) * 64 + j];
    float v = fmaxf(acc, 0.f) * w2[j];
    #pragma unroll
    for (int off = 32; off > 0; off >>= 1) v += __shfl_down(v, off, 64);
    if (j == 0) out[g] = 1.0f / (1.0f + expf(-(v + b2[0])));
}

extern "C" void kernel_launch(void* const* d_in, const int* in_sizes, int n_in,
                              void* d_out, int out_size, void* d_ws, size_t ws_size,
                              hipStream_t stream) {
    const float* mol_x   = (const float*)d_in[0];
    const int*   mol_ei  = (const int*)d_in[1];
    const int*   mol_bat = (const int*)d_in[2];
    const float* prot_x  = (const float*)d_in[3];
    const int*   prot_ei = (const int*)d_in[4];
    const float* gcn_w1  = (const float*)d_in[5];
    const float* gcn_b1  = (const float*)d_in[6];
    const float* gcn_w2  = (const float*)d_in[7];
    const float* gcn_b2  = (const float*)d_in[8];
    const float* gat_w1  = (const float*)d_in[9];
    const float* gat_as1 = (const float*)d_in[10];
    const float* gat_ad1 = (const float*)d_in[11];
    const float* gat_b1  = (const float*)d_in[12];
    const float* gat_w2  = (const float*)d_in[13];
    const float* gat_as2 = (const float*)d_in[14];
    const float* gat_ad2 = (const float*)d_in[15];
    const float* gat_b2  = (const float*)d_in[16];
    const float* cls_w1  = (const float*)d_in[17];
    const float* cls_b1  = (const float*)d_in[18];
    const float* cls_w2  = (const float*)d_in[19];
    const float* cls_b2  = (const float*)d_in[20];
    float* out = (float*)d_out;

    float* ws_f = (float*)d_ws;

    // ---- persistent tail; [gstart .. coarseP+512) is one contiguous zeroed region ----
    float* T       = ws_f + 16777216;
    float* gsum    = T;                       // 262,144 floats (no init needed)
    int*   gstart  = (int*)(T + 262144);      // 4,096 ints (zeroed)
    int*   gend    = (int*)(T + 266240);      // 4,096 ints (zeroed)
    float* psum    = T + 270336;              // 64 floats (zeroed)
    int*   coarseM = (int*)(T + 270400);      // 512 ints (zeroed)
    int*   coarseP = (int*)(T + 270912);      // 512 ints (zeroed)
    int*   cstartM = (int*)(T + 271424);      // 513
    int*   cursorM = (int*)(T + 271937);      // 512
    int*   cstartP = (int*)(T + 272449);      // 513
    int*   cursorP = (int*)(T + 272962);      // 512

    // ---- early CSR staging (both dead before molout is written) ----
    unsigned* bufM = (unsigned*)ws_f;                    // [0, 524,288)
    unsigned* bufP = (unsigned*)(ws_f + 524352);         // [524,352, 2,124,416)

    // ---- mol-phase layout ----
    float*    molout = ws_f;                             // [0, 8,388,608) (written late)
    __half*   h2hM   = (__half*)(ws_f + 8388608);        // [8,388,608, 12,582,912)
    int*      molCOL = (int*)(ws_f + 12582912);          // EM+64 -> 13,107,264
    int*      molRP  = (int*)(ws_f + 13107264);          // NM -> 13,238,336 (+pad)
    float*    dinvM  = ws_f + 13238352;                  // NM -> 13,369,424 (+pad)
    __half*   x8h    = (__half*)(ws_f + 13369440);       // NM*8 halves -> 13,893,728 (+pad)
    float*    aggM   = ws_f + 13893792;                  // NM*6 -> 14,680,224

    // ---- prot CSR outputs: mol-phase dead zone, survive the whole mol phase ----
    int*      protCOL = (int*)(ws_f + 14680256);         // EP+64 -> 16,280,320
    int*      protRP  = (int*)(ws_f + 16280320);         // NP -> 16,380,336

    // ---- prot-phase arrays (written only after mol phase completes) ----
    float*    protout = ws_f;                            // [0, 6,400,000)
    __half*   h2hP    = (__half*)(ws_f + 6400000);       // [6,400,000, 9,600,000)
    float*    es      = ws_f + 9600000;                  // NP
    float*    ed_     = ws_f + 9700000;                  // NP
    __half*   x32h    = (__half*)(ws_f + 9800000);       // NP*32 halves -> 11,400,000
    float*    aggP    = ws_f + 11400000;                 // NP*20 -> 13,400,000

    // single upfront zero of gstart+gend+psum+coarseM+coarseP (contiguous)
    (void)hipMemsetAsync(gstart, 0, (size_t)(4096 + 4096 + 64 + 512 + 512) * sizeof(int), stream);

    // ================= merged CSR build (mol + prot) =================
    k_hist2<<<256 + 391, 256, 0, stream>>>(mol_ei + EM, prot_ei + EP, coarseM, coarseP);
    k_scan2<<<2, 512, 0, stream>>>(coarseM, cstartM, cursorM, coarseP, cstartP, cursorP);
    k_part2<<<128 + 391, 256, 0, stream>>>(mol_ei, cursorM, bufM, prot_ei, cursorP, bufP);
    k_fine2<<<512 + 391, 256, 0, stream>>>(bufM, cstartM, molRP, molCOL, dinvM,
                                           bufP, cstartP, protRP, protCOL);

    // ================= mol branch =================
    k_molprep<<<2*cdiv(NM,256),256,0,stream>>>(mol_x, dinvM, x8h, mol_bat, gstart, gend, NM, cdiv(NM,256));
    k_gather_x8<<<NM/32,256,0,stream>>>(molRP, molCOL, x8h, dinvM, aggM);
    k_mlp<6,0,1><<<NM/16,256,0,stream>>>(aggM, gcn_w1, gcn_b1, gcn_w2, nullptr, nullptr, h2hM, nullptr, nullptr, dinvM);
    k_gather64h_gcn<<<NM/4,256,0,stream>>>(molRP, molCOL, h2hM, dinvM, gcn_b2, molout);
    k_segpool<<<NG,64,0,stream>>>(gstart, gend, molout, gsum);

    // ================= prot branch =================
    k_prep_prot<<<cdiv(NP,256),256,0,stream>>>(prot_x, gat_w1, gat_as1, gat_ad1, x32h, es, ed_, NP);
    k_gather_x32<<<NP/4,256,0,stream>>>(protRP, protCOL, x32h, es, ed_, aggP);
    k_mlp<20,1,0><<<NP/16,256,0,stream>>>(aggP, gat_w1, gat_b1, gat_w2, gat_as2, gat_ad2, h2hP, es, ed_, nullptr);
    k_gather64h_gat<<<NP/4,256,0,stream>>>(protRP, protCOL, h2hP, es, ed_, gat_b2, protout);
    k_pool_prot<<<1024,256,0,stream>>>(protout, psum, NP);

    // ================= classifier =================
    k_cls<<<NG/4,256,0,stream>>>(gsum, gstart, gend, psum, cls_w1, cls_b1, cls_w2, cls_b2, out);
}

// Round 17
// 405.391 us; speedup vs baseline: 1.2872x; 1.0489x over previous
//
#include <hip/hip_runtime.h>
#include <hip/hip_fp16.h>

#define NM 131072   // mol nodes
#define EM 524288   // mol edges
#define NG 4096     // graphs
#define DM 6        // mol in dim
#define NP 100000   // prot nodes
#define EP 1600000  // prot edges
#define DP 20       // prot in dim

static inline int cdiv(int a, int b){ return (a + b - 1) / b; }

__device__ __forceinline__ float leaky(float x){ return x > 0.f ? x : 0.2f * x; }

union H8 { float4 f4; __half2 h2[4]; };

// ================= merged bucketed CSR build (round-16, proven) =================
__global__ void k_hist2(const int* __restrict__ dstM, const int* __restrict__ dstP,
                        int* __restrict__ coarseM, int* __restrict__ coarseP){
    __shared__ int lh[512];
    int t = threadIdx.x;
    const int* dst; int* coarse; int K, E, base, chunk;
    if (blockIdx.x < 256) { dst = dstM; coarse = coarseM; K = 512; E = EM; chunk = 2048; base = blockIdx.x * 2048; }
    else                  { dst = dstP; coarse = coarseP; K = 391; E = EP; chunk = 4096; base = (blockIdx.x - 256) * 4096; }
    for (int i = t; i < K; i += 256) lh[i] = 0;
    __syncthreads();
    int end = min(base + chunk, E);
    for (int e = base + t; e < end; e += 256)
        atomicAdd(&lh[dst[e] >> 8], 1);
    __syncthreads();
    for (int i = t; i < K; i += 256)
        if (lh[i]) atomicAdd(&coarse[i], lh[i]);
}

__global__ void k_scan2(const int* __restrict__ coarseM, int* __restrict__ cstartM, int* __restrict__ cursorM,
                        const int* __restrict__ coarseP, int* __restrict__ cstartP, int* __restrict__ cursorP){
    const int* coarse; int* cstart; int* cursor; int K;
    if (blockIdx.x == 0) { coarse = coarseM; cstart = cstartM; cursor = cursorM; K = 512; }
    else                 { coarse = coarseP; cstart = cstartP; cursor = cursorP; K = 391; }
    int t = threadIdx.x, lane = t & 63, wid = t >> 6;
    int v0 = (t < K) ? coarse[t] : 0;
    int v = v0;
    #pragma unroll
    for (int off = 1; off < 64; off <<= 1) {
        int x = __shfl_up(v, off, 64);
        if (lane >= off) v += x;
    }
    __shared__ int ws[8];
    if (lane == 63) ws[wid] = v;
    __syncthreads();
    int add = 0;
    for (int w = 0; w < wid; w++) add += ws[w];
    int excl = v + add - v0;
    if (t < K) { cstart[t] = excl; cursor[t] = excl; }
    if (t == K - 1) cstart[K] = excl + v0;
}

__global__ void k_part2(const int* __restrict__ eiM, int* __restrict__ cursorM, unsigned* __restrict__ bufM,
                        const int* __restrict__ eiP, int* __restrict__ cursorP, unsigned* __restrict__ bufP){
    __shared__ int lh[512];
    __shared__ int lbase[512];
    const int* ei; int* cursor; unsigned* buf; int E, K, base;
    if (blockIdx.x < 128) { ei = eiM; cursor = cursorM; buf = bufM; E = EM; K = 512; base = blockIdx.x * 4096; }
    else                  { ei = eiP; cursor = cursorP; buf = bufP; E = EP; K = 391; base = (blockIdx.x - 128) * 4096; }
    int t = threadIdx.x;
    for (int i = t; i < K; i += 256) lh[i] = 0;
    __syncthreads();
    int end = min(base + 4096, E);
    unsigned pay[16]; int bslot[16];
    int cnt = 0;
    for (int e = base + t; e < end; e += 256) {
        int u = ei[e], v = ei[E + e];
        int b = v >> 8;
        int ls = atomicAdd(&lh[b], 1);
        pay[cnt] = ((unsigned)(v & 255) << 24) | (unsigned)u;
        bslot[cnt] = (b << 13) | ls;
        cnt++;
    }
    __syncthreads();
    for (int i = t; i < K; i += 256)
        lbase[i] = lh[i] ? atomicAdd(&cursor[i], lh[i]) : 0;
    __syncthreads();
    for (int j = 0; j < cnt; j++) {
        int b = bslot[j] >> 13, ls = bslot[j] & 8191;
        buf[lbase[b] + ls] = pay[j];
    }
}

__global__ void k_fine2(const unsigned* __restrict__ bufM, const int* __restrict__ cstartM,
                        int* __restrict__ molRP, int* __restrict__ molCOL, float* __restrict__ dinv,
                        const unsigned* __restrict__ bufP, const int* __restrict__ cstartP,
                        int* __restrict__ protRP, int* __restrict__ protCOL){
    int t = threadIdx.x;
    int k; const unsigned* buf; const int* cstart; int* rp; int* col; int n, OB, dv;
    if (blockIdx.x < 512) { k = blockIdx.x;       buf = bufM; cstart = cstartM; rp = molRP;  col = molCOL;  n = NM; OB = 20; dv = 1; }
    else                  { k = blockIdx.x - 512; buf = bufP; cstart = cstartP; rp = protRP; col = protCOL; n = NP; OB = 21; dv = 0; }
    int start = cstart[k], end = cstart[k + 1];
    __shared__ int cnt[256];
    __shared__ int cur[256];
    cnt[t] = 0;
    __syncthreads();
    for (int p = start + t; p < end; p += 256)
        atomicAdd(&cnt[buf[p] >> 24], 1);
    __syncthreads();
    int v0 = cnt[t];
    int lane = t & 63, wid = t >> 6;
    int v = v0;
    #pragma unroll
    for (int off = 1; off < 64; off <<= 1) {
        int x = __shfl_up(v, off, 64);
        if (lane >= off) v += x;
    }
    __shared__ int ws[4];
    if (lane == 63) ws[wid] = v;
    __syncthreads();
    int add = 0;
    for (int w = 0; w < wid; w++) add += ws[w];
    int excl = v + add - v0;
    int ofs = start + excl;
    cur[t] = ofs;
    int idx = (k << 8) + t;
    if (idx < n) {
        rp[idx] = (int)((unsigned)ofs | ((unsigned)v0 << OB));
        if (dv) dinv[idx] = rsqrtf((float)(v0 + 1));
    }
    __syncthreads();
    for (int p = start + t; p < end; p += 256) {
        unsigned pk = buf[p];
        int slot = atomicAdd(&cur[pk >> 24], 1);
        col[slot] = (int)(pk & 0xFFFFFFu);
    }
}

// ================= merged prep: molprep (512) + segbounds (512) + prot prep (391) =================
__global__ void k_prep2(const float* __restrict__ mol_x, const float* __restrict__ dinv,
                        __half* __restrict__ x8, const int* __restrict__ batch,
                        int* __restrict__ gstart, int* __restrict__ gend,
                        const float* __restrict__ prot_x, const float* __restrict__ W1,
                        const float* __restrict__ as_, const float* __restrict__ ad_,
                        __half* __restrict__ x32, float* __restrict__ es,
                        float* __restrict__ ed_){
    __shared__ float vas[20], vds[20];
    int b = blockIdx.x, t = threadIdx.x;
    if (b < 512) {
        int i = b * 256 + t;
        float dd = dinv[i];
        H8 r;
        #pragma unroll
        for (int k = 0; k < 3; k++)
            r.h2[k] = __floats2half2_rn(dd * mol_x[i*6 + 2*k], dd * mol_x[i*6 + 2*k + 1]);
        r.h2[3] = __floats2half2_rn(0.f, 0.f);
        *(float4*)&x8[(size_t)i * 8] = r.f4;
    } else if (b < 1024) {
        int i = (b - 512) * 256 + t;
        int g = batch[i];
        if (i == 0 || batch[i - 1] != g) gstart[g] = i;
        if (i == NM - 1 || batch[i + 1] != g) gend[g] = i + 1;
    } else {
        if (t < 20) {
            float s = 0.f;
            for (int j = 0; j < 64; j++) s += W1[t * 64 + j] * as_[j];
            vas[t] = s;
        } else if (t >= 32 && t < 52) {
            int k = t - 32;
            float s = 0.f;
            for (int j = 0; j < 64; j++) s += W1[k * 64 + j] * ad_[j];
            vds[k] = s;
        }
        __syncthreads();
        int i = (b - 1024) * 256 + t;
        if (i >= NP) return;
        float xv[20];
        float s = 0.f, d = 0.f;
        #pragma unroll
        for (int k = 0; k < 20; k++) {
            xv[k] = prot_x[i*20 + k];
            s += xv[k] * vas[k]; d += xv[k] * vds[k];
        }
        es[i] = s; ed_[i] = d;
        H8 r0, r1, r2, rz;
        #pragma unroll
        for (int k = 0; k < 4; k++) r0.h2[k] = __floats2half2_rn(xv[2*k],   xv[2*k+1]);
        #pragma unroll
        for (int k = 0; k < 4; k++) r1.h2[k] = __floats2half2_rn(xv[8+2*k], xv[9+2*k]);
        r2.h2[0] = __floats2half2_rn(xv[16], xv[17]);
        r2.h2[1] = __floats2half2_rn(xv[18], xv[19]);
        r2.h2[2] = __floats2half2_rn(0.f, 0.f);
        r2.h2[3] = __floats2half2_rn(0.f, 0.f);
        rz.h2[0] = rz.h2[1] = rz.h2[2] = rz.h2[3] = __floats2half2_rn(0.f, 0.f);
        *(float4*)&x32[(size_t)i * 32]      = r0.f4;
        *(float4*)&x32[(size_t)i * 32 + 8]  = r1.f4;
        *(float4*)&x32[(size_t)i * 32 + 16] = r2.f4;
        *(float4*)&x32[(size_t)i * 32 + 24] = rz.f4;
    }
}

// ================= merged L1 gathers: mol (4096 blocks) + prot (25000 blocks) =================
__global__ void k_l1g2(const int* __restrict__ molRP, const int* __restrict__ molCOL,
                       const __half* __restrict__ x8, const float* __restrict__ dinv,
                       float* __restrict__ aggM,
                       const int* __restrict__ protRP, const int* __restrict__ protCOL,
                       const __half* __restrict__ x32, const float* __restrict__ es,
                       const float* __restrict__ ed_, float* __restrict__ aggP){
    __shared__ float ost[192];
    int tid = threadIdx.x;
    if (blockIdx.x < NM/32) {
        int bid = blockIdx.x;
        int wv = tid >> 6, l = tid & 63, g = l >> 3, q = l & 7;
        int node = (bid << 5) + (wv << 3) + g;
        unsigned pk = (unsigned)molRP[node];
        int s0 = (int)(pk & 0xFFFFFu);
        int deg = (int)(pk >> 20);
        float acc[6] = {0.f,0.f,0.f,0.f,0.f,0.f};
        if (q == 0) {
            H8 r; r.f4 = *(const float4*)&x8[(size_t)node * 8];
            #pragma unroll
            for (int i = 0; i < 3; i++) {
                float2 f = __half22float2(r.h2[i]);
                acc[2*i] = f.x; acc[2*i+1] = f.y;
            }
        }
        for (int base = 0; base < deg; base += 8) {
            int s = base + q;
            int c = molCOL[s0 + s];
            int u = (s < deg) ? c : node;
            float wvv = (s < deg) ? 1.f : 0.f;
            H8 r; r.f4 = *(const float4*)&x8[(size_t)u * 8];
            #pragma unroll
            for (int i = 0; i < 3; i++) {
                float2 f = __half22float2(r.h2[i]);
                acc[2*i] += wvv * f.x; acc[2*i+1] += wvv * f.y;
            }
        }
        #pragma unroll
        for (int m = 1; m < 8; m <<= 1) {
            #pragma unroll
            for (int i = 0; i < 6; i++) acc[i] += __shfl_xor(acc[i], m, 8);
        }
        if (q == 0) {
            float dd = dinv[node];
            int slot = (wv << 3) + g;
            #pragma unroll
            for (int i = 0; i < 6; i++) ost[slot * 6 + i] = dd * acc[i];
        }
        __syncthreads();
        if (tid < 48)
            *(float4*)&aggM[(size_t)bid * 192 + (tid << 2)] = *(float4*)&ost[tid << 2];
    } else {
        int bid = blockIdx.x - NM/32;
        int node = (bid << 2) + (tid >> 6);
        int l = tid & 63, g = l >> 2, q = l & 3;
        unsigned pk = (unsigned)protRP[node];
        int s0 = (int)(pk & 0x1FFFFFu);
        int deg = (int)(pk >> 21);
        float edv = ed_[node];
        float selfw = __expf(leaky(es[node] + edv));
        float acc[8] = {0.f,0.f,0.f,0.f,0.f,0.f,0.f,0.f};
        float den = (l == 0) ? selfw : 0.f;
        if (g == 0 && q < 3) {
            H8 r; r.f4 = *(const float4*)&x32[(size_t)node * 32 + (q << 3)];
            #pragma unroll
            for (int i = 0; i < 4; i++) {
                float2 f = __half22float2(r.h2[i]);
                acc[2*i] = selfw * f.x; acc[2*i+1] = selfw * f.y;
            }
        }
        for (int base = 0; base < deg; base += 16) {
            int s = base + g;
            int c = protCOL[s0 + s];
            int u = (s < deg) ? c : node;
            float wvv = (s < deg) ? __expf(leaky(es[u] + edv)) : 0.f;
            if (q < 3) {
                H8 r; r.f4 = *(const float4*)&x32[(size_t)u * 32 + (q << 3)];
                #pragma unroll
                for (int i = 0; i < 4; i++) {
                    float2 f = __half22float2(r.h2[i]);
                    acc[2*i] += wvv * f.x; acc[2*i+1] += wvv * f.y;
                }
            }
            if (q == 0) den += wvv;
        }
        #pragma unroll
        for (int m = 4; m <= 32; m <<= 1) {
            #pragma unroll
            for (int i = 0; i < 8; i++) acc[i] += __shfl_xor(acc[i], m, 64);
            den += __shfl_xor(den, m, 64);
        }
        den = __shfl(den, 0, 64);
        float inv = 1.f / den;
        if (g == 0) {
            if (q < 2) {
                float4 v0 = make_float4(acc[0]*inv, acc[1]*inv, acc[2]*inv, acc[3]*inv);
                float4 v1 = make_float4(acc[4]*inv, acc[5]*inv, acc[6]*inv, acc[7]*inv);
                *(float4*)&aggP[(size_t)node * 20 + (q << 3)]     = v0;
                *(float4*)&aggP[(size_t)node * 20 + (q << 3) + 4] = v1;
            } else if (q == 2) {
                float4 v0 = make_float4(acc[0]*inv, acc[1]*inv, acc[2]*inv, acc[3]*inv);
                *(float4*)&aggP[(size_t)node * 20 + 16] = v0;
            }
        }
    }
}

// ================= merged MLP (templated body, shared smem pool) =================
template<int D, int ATT, int SCALE>
__device__ __forceinline__ void mlp_body(float* smem, int bid, int tid,
                                         const float* __restrict__ agg, const float* __restrict__ W1,
                                         const float* __restrict__ b1, const float* __restrict__ W2,
                                         const float* __restrict__ as_, const float* __restrict__ ad_,
                                         __half* __restrict__ hout, float* __restrict__ es,
                                         float* __restrict__ ed_, const float* __restrict__ dinv){
    float* W1s = smem;                    // D*64
    float* W2s = smem + D * 64;           // 4096
    float* A   = W2s + 4096;              // 16*(D+1)
    float* X1  = A + 16 * (D + 1);        // 16*68
    for (int k = tid; k < D * 64; k += 256) W1s[k] = W1[k];
    for (int k = tid * 4; k < 4096; k += 1024)
        *(float4*)&W2s[k] = *(const float4*)&W2[k];
    int nd = tid >> 4, q = tid & 15;
    size_t node = (size_t)bid * 16 + nd;
    for (int k = q; k < D; k += 16) A[nd * (D + 1) + k] = agg[node * D + k];
    __syncthreads();
    float4 h1 = *(const float4*)&b1[q << 2];
    #pragma unroll
    for (int k = 0; k < D; k++) {
        float xk = A[nd * (D + 1) + k];
        float4 w4 = *(const float4*)&W1s[(k << 6) + (q << 2)];
        h1.x += xk * w4.x; h1.y += xk * w4.y; h1.z += xk * w4.z; h1.w += xk * w4.w;
    }
    h1.x = fmaxf(h1.x, 0.f); h1.y = fmaxf(h1.y, 0.f);
    h1.z = fmaxf(h1.z, 0.f); h1.w = fmaxf(h1.w, 0.f);
    *(float4*)&X1[nd * 68 + (q << 2)] = h1;
    __syncthreads();
    float4 acc = {0.f, 0.f, 0.f, 0.f};
    #pragma unroll 8
    for (int k = 0; k < 64; k++) {
        float xk = X1[nd * 68 + k];
        float4 w4 = *(const float4*)&W2s[(k << 6) + (q << 2)];
        acc.x += xk * w4.x; acc.y += xk * w4.y; acc.z += xk * w4.z; acc.w += xk * w4.w;
    }
    float4 st = acc;
    if (SCALE) {
        float dd = dinv[node];
        st.x *= dd; st.y *= dd; st.z *= dd; st.w *= dd;
    }
    union { __half2 h2[2]; float2 f2; } u;
    u.h2[0] = __floats2half2_rn(st.x, st.y);
    u.h2[1] = __floats2half2_rn(st.z, st.w);
    *(float2*)&hout[node * 64 + (q << 2)] = u.f2;
    if (ATT) {
        int f = q << 2;
        float xa = acc.x * as_[f] + acc.y * as_[f + 1] + acc.z * as_[f + 2] + acc.w * as_[f + 3];
        float ya = acc.x * ad_[f] + acc.y * ad_[f + 1] + acc.z * ad_[f + 2] + acc.w * ad_[f + 3];
        #pragma unroll
        for (int m = 1; m < 16; m <<= 1) {
            xa += __shfl_xor(xa, m, 16);
            ya += __shfl_xor(ya, m, 16);
        }
        if (q == 0) { es[node] = xa; ed_[node] = ya; }
    }
}

__global__ void k_mlp2(const float* __restrict__ aggM, const float* __restrict__ gcn_w1,
                       const float* __restrict__ gcn_b1, const float* __restrict__ gcn_w2,
                       __half* __restrict__ h2hM, const float* __restrict__ dinvM,
                       const float* __restrict__ aggP, const float* __restrict__ gat_w1,
                       const float* __restrict__ gat_b1, const float* __restrict__ gat_w2,
                       const float* __restrict__ as2, const float* __restrict__ ad2,
                       __half* __restrict__ h2hP, float* __restrict__ es, float* __restrict__ ed_){
    __shared__ float smem[6800];   // prot: 1280+4096+336+1088 = 6800 (mol needs 5680)
    if (blockIdx.x < NM/16)
        mlp_body<6,0,1>(smem, blockIdx.x, threadIdx.x, aggM, gcn_w1, gcn_b1, gcn_w2,
                        nullptr, nullptr, h2hM, nullptr, nullptr, dinvM);
    else
        mlp_body<20,1,0>(smem, blockIdx.x - NM/16, threadIdx.x, aggP, gat_w1, gat_b1, gat_w2,
                         as2, ad2, h2hP, es, ed_, nullptr);
}

// ---------------- prot layer-2 gather: 8 groups x 8 lanes, 2 slots/group, fp16 out ----------------
__global__ void k_gather64h_gat(const int* __restrict__ rp, const int* __restrict__ col,
                                const __half* __restrict__ hh, const float* __restrict__ es,
                                const float* __restrict__ ed_, const float* __restrict__ b,
                                __half* __restrict__ out_h){
    int tid = threadIdx.x;
    int node = (blockIdx.x << 2) + (tid >> 6);
    int l = tid & 63, g = l >> 3, q = l & 7;
    unsigned pk = (unsigned)rp[node];
    int s0 = (int)(pk & 0x1FFFFFu);
    int deg = (int)(pk >> 21);
    float edv = ed_[node];
    float selfw = __expf(leaky(es[node] + edv));
    float acc[8] = {0.f,0.f,0.f,0.f,0.f,0.f,0.f,0.f};
    float den = (l == 0) ? selfw : 0.f;
    if (g == 0) {
        H8 r; r.f4 = *(const float4*)&hh[(size_t)node * 64 + (q << 3)];
        #pragma unroll
        for (int i = 0; i < 4; i++) {
            float2 f = __half22float2(r.h2[i]);
            acc[2*i]     = selfw * f.x;
            acc[2*i + 1] = selfw * f.y;
        }
    }
    for (int base = 0; base < deg; base += 16) {
        int sA = base + g, sB = base + g + 8;
        int cA = col[s0 + sA], cB = col[s0 + sB];
        int uA = (sA < deg) ? cA : node;
        int uB = (sB < deg) ? cB : node;
        float eA = es[uA], eB = es[uB];
        float wA = (sA < deg) ? __expf(leaky(eA + edv)) : 0.f;
        float wB = (sB < deg) ? __expf(leaky(eB + edv)) : 0.f;
        H8 rA, rB;
        rA.f4 = *(const float4*)&hh[(size_t)uA * 64 + (q << 3)];
        rB.f4 = *(const float4*)&hh[(size_t)uB * 64 + (q << 3)];
        #pragma unroll
        for (int i = 0; i < 4; i++) {
            float2 fA = __half22float2(rA.h2[i]);
            float2 fB = __half22float2(rB.h2[i]);
            acc[2*i]     += wA * fA.x + wB * fB.x;
            acc[2*i + 1] += wA * fA.y + wB * fB.y;
        }
        if (q == 0) den += wA + wB;
    }
    #pragma unroll
    for (int m = 8; m <= 32; m <<= 1) {
        #pragma unroll
        for (int i = 0; i < 8; i++) acc[i] += __shfl_xor(acc[i], m, 64);
        den += __shfl_xor(den, m, 64);
    }
    den = __shfl(den, 0, 64);
    if (g == 0) {
        float sc = 1.f / den;
        int f = q << 3;
        H8 o;
        #pragma unroll
        for (int i = 0; i < 4; i++)
            o.h2[i] = __floats2half2_rn(acc[2*i]*sc + b[f + 2*i], acc[2*i+1]*sc + b[f + 2*i + 1]);
        *(float4*)&out_h[(size_t)node * 64 + f] = o.f4;
    }
}

// ---------------- mol layer-2 gather: 8 slots x 8 lanes, pre-scaled rows, fp16 out ----------------
__global__ void k_gather64h_gcn(const int* __restrict__ rp, const int* __restrict__ col,
                                const __half* __restrict__ hh, const float* __restrict__ dinv,
                                const float* __restrict__ b, __half* __restrict__ out_h){
    int tid = threadIdx.x;
    int node = (blockIdx.x << 2) + (tid >> 6);
    int l = tid & 63, g = l >> 3, q = l & 7;
    unsigned pk = (unsigned)rp[node];
    int s0 = (int)(pk & 0xFFFFFu);
    int deg = (int)(pk >> 20);
    float acc[8] = {0.f,0.f,0.f,0.f,0.f,0.f,0.f,0.f};
    if (g == 0) {
        H8 r; r.f4 = *(const float4*)&hh[(size_t)node * 64 + (q << 3)];
        #pragma unroll
        for (int i = 0; i < 4; i++) {
            float2 f = __half22float2(r.h2[i]);
            acc[2*i]     = f.x;
            acc[2*i + 1] = f.y;
        }
    }
    for (int base = 0; base < deg; base += 8) {
        int s = base + g;
        int c = col[s0 + s];
        int u = (s < deg) ? c : node;
        float wvv = (s < deg) ? 1.f : 0.f;
        H8 r; r.f4 = *(const float4*)&hh[(size_t)u * 64 + (q << 3)];
        #pragma unroll
        for (int i = 0; i < 4; i++) {
            float2 f = __half22float2(r.h2[i]);
            acc[2*i]     += wvv * f.x;
            acc[2*i + 1] += wvv * f.y;
        }
    }
    #pragma unroll
    for (int m = 8; m <= 32; m <<= 1) {
        #pragma unroll
        for (int i = 0; i < 8; i++) acc[i] += __shfl_xor(acc[i], m, 64);
    }
    if (g == 0) {
        float sc = dinv[node];
        int f = q << 3;
        H8 o;
        #pragma unroll
        for (int i = 0; i < 4; i++)
            o.h2[i] = __floats2half2_rn(acc[2*i]*sc + b[f + 2*i], acc[2*i+1]*sc + b[f + 2*i + 1]);
        *(float4*)&out_h[(size_t)node * 64 + f] = o.f4;
    }
}

// ================= merged pools: segpool fp16 (1024 blocks) + prot pool fp16 (1024) =================
__global__ void k_pool2(const int* __restrict__ gstart, const int* __restrict__ gend,
                        const __half* __restrict__ molout_h, float* __restrict__ gsum,
                        const __half* __restrict__ protout_h, float* __restrict__ psum){
    __shared__ float red[4][64];
    int t = threadIdx.x;
    if (blockIdx.x < 1024) {
        // 4 graphs per block, one wave each
        int wv = t >> 6, l = t & 63, rg = l >> 4, q = l & 15;
        int gph = (blockIdx.x << 2) + wv;
        int s = gstart[gph], c = gend[gph] - gstart[gph];
        float4 a = {0.f, 0.f, 0.f, 0.f};
        for (int i = rg; i < c; i += 4) {
            __half2 h0 = *(const __half2*)&molout_h[(size_t)(s + i) * 64 + (q << 2)];
            __half2 h1 = *(const __half2*)&molout_h[(size_t)(s + i) * 64 + (q << 2) + 2];
            float2 f0 = __half22float2(h0), f1 = __half22float2(h1);
            a.x += f0.x; a.y += f0.y; a.z += f1.x; a.w += f1.y;
        }
        #pragma unroll
        for (int m = 16; m <= 32; m <<= 1) {
            a.x += __shfl_xor(a.x, m, 64);
            a.y += __shfl_xor(a.y, m, 64);
            a.z += __shfl_xor(a.z, m, 64);
            a.w += __shfl_xor(a.w, m, 64);
        }
        if (rg == 0) *(float4*)&gsum[gph * 64 + (q << 2)] = a;
    } else {
        // grid-stride over NP*8 chunks of 8 halves; phase = chunk & 7
        const float4* p4 = (const float4*)protout_h;
        const int TC = NP * 8;
        float acc[8] = {0.f,0.f,0.f,0.f,0.f,0.f,0.f,0.f};
        for (int i = (blockIdx.x - 1024) * 256 + t; i < TC; i += 1024 * 256) {
            H8 r; r.f4 = p4[i];
            #pragma unroll
            for (int j = 0; j < 4; j++) {
                float2 f = __half22float2(r.h2[j]);
                acc[2*j] += f.x; acc[2*j+1] += f.y;
            }
        }
        int lane = t & 63, wv = t >> 6;
        #pragma unroll
        for (int m = 8; m <= 32; m <<= 1) {
            #pragma unroll
            for (int j = 0; j < 8; j++) acc[j] += __shfl_xor(acc[j], m, 64);
        }
        if (lane < 8) {
            #pragma unroll
            for (int j = 0; j < 8; j++) red[wv][lane * 8 + j] = acc[j];
        }
        __syncthreads();
        if (t < 64) {
            float s = red[0][t] + red[1][t] + red[2][t] + red[3][t];
            atomicAdd(&psum[t], s);
        }
    }
}

// ---------------- fused classifier ----------------
__global__ void k_cls(const float* __restrict__ gsum, const int* __restrict__ gstart,
                      const int* __restrict__ gend, const float* __restrict__ psum,
                      const float* __restrict__ W1, const float* __restrict__ b1,
                      const float* __restrict__ w2, const float* __restrict__ b2,
                      float* __restrict__ out){
    __shared__ float W1s[128 * 64];
    int tid = threadIdx.x;
    for (int k = tid; k < 128 * 64; k += 256) W1s[k] = W1[k];
    __syncthreads();
    int g = blockIdx.x * 4 + (tid >> 6);
    int j = tid & 63;
    float cntf = (float)(gend[g] - gstart[g]);
    float inv = 1.0f / fmaxf(cntf, 1.0f);
    const float invp = 1.0f / (float)NP;
    float acc = b1[j];
    #pragma unroll 8
    for (int k = 0; k < 64; k++) acc += (gsum[g * 64 + k] * inv) * W1s[k * 64 + j];
    #pragma unroll 8
    for (int k = 0; k < 64; k++) acc += (psum[k] * invp) * W1s[(64 + k) * 64 + j];
    float v = fmaxf(acc, 0.f) * w2[j];
    #pragma unroll
    for (int off = 32; off > 0; off >>= 1) v += __shfl_down(v, off, 64);
    if (j == 0) out[g] = 1.0f / (1.0f + expf(-(v + b2[0])));
}

extern "C" void kernel_launch(void* const* d_in, const int* in_sizes, int n_in,
                              void* d_out, int out_size, void* d_ws, size_t ws_size,
                              hipStream_t stream) {
    const float* mol_x   = (const float*)d_in[0];
    const int*   mol_ei  = (const int*)d_in[1];
    const int*   mol_bat = (const int*)d_in[2];
    const float* prot_x  = (const float*)d_in[3];
    const int*   prot_ei = (const int*)d_in[4];
    const float* gcn_w1  = (const float*)d_in[5];
    const float* gcn_b1  = (const float*)d_in[6];
    const float* gcn_w2  = (const float*)d_in[7];
    const float* gcn_b2  = (const float*)d_in[8];
    const float* gat_w1  = (const float*)d_in[9];
    const float* gat_as1 = (const float*)d_in[10];
    const float* gat_ad1 = (const float*)d_in[11];
    const float* gat_b1  = (const float*)d_in[12];
    const float* gat_w2  = (const float*)d_in[13];
    const float* gat_as2 = (const float*)d_in[14];
    const float* gat_ad2 = (const float*)d_in[15];
    const float* gat_b2  = (const float*)d_in[16];
    const float* cls_w1  = (const float*)d_in[17];
    const float* cls_b1  = (const float*)d_in[18];
    const float* cls_w2  = (const float*)d_in[19];
    const float* cls_b2  = (const float*)d_in[20];
    float* out = (float*)d_out;

    float* ws_f = (float*)d_ws;

    // ---- persistent tail; [gstart .. coarseP+512) is one contiguous zeroed region ----
    float* T       = ws_f + 16777216;
    float* gsum    = T;                       // 262,144 floats (no init needed)
    int*   gstart  = (int*)(T + 262144);      // 4,096 ints (zeroed)
    int*   gend    = (int*)(T + 266240);      // 4,096 ints (zeroed)
    float* psum    = T + 270336;              // 64 floats (zeroed)
    int*   coarseM = (int*)(T + 270400);      // 512 ints (zeroed)
    int*   coarseP = (int*)(T + 270912);      // 512 ints (zeroed)
    int*   cstartM = (int*)(T + 271424);      // 513
    int*   cursorM = (int*)(T + 271937);      // 512
    int*   cstartP = (int*)(T + 272449);      // 513
    int*   cursorP = (int*)(T + 272962);      // 512

    // ---- early CSR staging (dead after k_fine2) ----
    unsigned* bufM = (unsigned*)ws_f;                    // [0, 524,288)
    unsigned* bufP = (unsigned*)(ws_f + 524352);         // [524,352, 2,124,416)

    // ---- overlapping phase regions (all offsets in floats) ----
    // [0, 3,200,000):          h2hP (fp16, NP*64) -- written by mlp2, read by gat, then dead
    // [0, 4,194,304):          molout_h (fp16, NM*64) -- written by gcn AFTER gat reads h2hP
    // [4,194,304, 5,794,304):  x32h (fp16, NP*32) -- dead after l1g2
    // [4,194,304, 7,394,304):  protout_h (fp16, NP*64) -- written by gat (x32h/aggP dead)
    // [5,794,304, 7,794,304):  aggP -- dead after mlp2
    // [7,794,304, 7,894,304):  es ; [7,894,304, 7,994,304): ed
    // [8,388,608, 12,582,912): h2hM (fp16, NM*64)
    __half*   h2hP      = (__half*)ws_f;
    __half*   molout_h  = (__half*)ws_f;
    __half*   x32h      = (__half*)(ws_f + 4194304);
    __half*   protout_h = (__half*)(ws_f + 4194304);
    float*    aggP      = ws_f + 5794304;
    float*    es        = ws_f + 7794304;
    float*    ed_       = ws_f + 7894304;
    __half*   h2hM      = (__half*)(ws_f + 8388608);
    int*      molCOL    = (int*)(ws_f + 12582912);       // EM+64 -> 13,107,264
    int*      molRP     = (int*)(ws_f + 13107264);       // NM -> 13,238,336 (+pad)
    float*    dinvM     = ws_f + 13238352;               // NM -> 13,369,424 (+pad)
    __half*   x8h       = (__half*)(ws_f + 13369440);    // NM*8 halves -> 13,893,728 (+pad)
    float*    aggM      = ws_f + 13893792;               // NM*6 -> 14,680,224 (+pad)
    int*      protCOL   = (int*)(ws_f + 14680256);       // EP+64 -> 16,280,320
    int*      protRP    = (int*)(ws_f + 16280320);       // NP -> 16,380,320

    // single upfront zero of gstart+gend+psum+coarseM+coarseP (contiguous)
    (void)hipMemsetAsync(gstart, 0, (size_t)(4096 + 4096 + 64 + 512 + 512) * sizeof(int), stream);

    // ================= merged CSR build (mol + prot) =================
    k_hist2<<<256 + 391, 256, 0, stream>>>(mol_ei + EM, prot_ei + EP, coarseM, coarseP);
    k_scan2<<<2, 512, 0, stream>>>(coarseM, cstartM, cursorM, coarseP, cstartP, cursorP);
    k_part2<<<128 + 391, 256, 0, stream>>>(mol_ei, cursorM, bufM, prot_ei, cursorP, bufP);
    k_fine2<<<512 + 391, 256, 0, stream>>>(bufM, cstartM, molRP, molCOL, dinvM,
                                           bufP, cstartP, protRP, protCOL);

    // ================= merged preps =================
    k_prep2<<<512 + 512 + 391, 256, 0, stream>>>(mol_x, dinvM, x8h, mol_bat, gstart, gend,
                                                 prot_x, gat_w1, gat_as1, gat_ad1, x32h, es, ed_);

    // ================= merged L1 gathers =================
    k_l1g2<<<NM/32 + NP/4, 256, 0, stream>>>(molRP, molCOL, x8h, dinvM, aggM,
                                             protRP, protCOL, x32h, es, ed_, aggP);

    // ================= merged MLPs =================
    k_mlp2<<<NM/16 + NP/16, 256, 0, stream>>>(aggM, gcn_w1, gcn_b1, gcn_w2, h2hM, dinvM,
                                              aggP, gat_w1, gat_b1, gat_w2, gat_as2, gat_ad2,
                                              h2hP, es, ed_);

    // ================= L2 gathers (gat first: gcn's molout_h overwrites h2hP) =================
    k_gather64h_gat<<<NP/4, 256, 0, stream>>>(protRP, protCOL, h2hP, es, ed_, gat_b2, protout_h);
    k_gather64h_gcn<<<NM/4, 256, 0, stream>>>(molRP, molCOL, h2hM, dinvM, gcn_b2, molout_h);

    // ================= merged pools =================
    k_pool2<<<1024 + 1024, 256, 0, stream>>>(gstart, gend, molout_h, gsum, protout_h, psum);

    // ================= classifier =================
    k_cls<<<NG/4, 256, 0, stream>>>(gsum, gstart, gend, psum, cls_w1, cls_b1, cls_w2, cls_b2, out);
}